// Round 15
// baseline (494.221 us; speedup 1.0000x reference)
//
#include <hip/hip_runtime.h>
#include <hip/hip_bf16.h>
#include <hip/hip_fp16.h>
#include <type_traits>

// ---------------------------------------------------------------------------
// 2-layer GCN. CSR-gather aggregation (fp16 features, fp32 accum, 4x-unrolled
// edge loop; dinv[d] factored out of edge vals -> applied once per node).
// Preprocessing: ONE 64-bit packed atomic per edge; dinv fused into scan1;
// cursor-based CSR fill.
// GEMM1: fp32 A, fused convert, A-prefetch DISTANCE 2. loadA issues EXACTLY
// 4 float2 loads per thread per step (clamped addresses + register selects
// for the K-tail) so the FIFO vmcnt counts are exact for every thread —
// R14's post-timing divergence was tail threads issuing <4 loads, making
// vmcnt(4) under-wait the B-tile DMA.
// GEMM2: fp16 A via global_load_lds (counted vmcnt(3), full drain per iter).
// Both: fp16 MFMA fp32-accum, double-buffered LDS, LDS-bounce epilogue.
// ---------------------------------------------------------------------------

typedef _Float16 f16x8 __attribute__((ext_vector_type(8)));
typedef float f32x4 __attribute__((ext_vector_type(4)));

#define DEG_MASK ((1ull << 42) - 1)

__device__ inline void async_copy16(const void* g, void* l) {
    __builtin_amdgcn_global_load_lds(
        (const __attribute__((address_space(1))) void*)g,
        (__attribute__((address_space(3))) void*)l, 16, 0, 0);
}

// ------------------------- graph preprocessing -----------------------------
// packed[i]: bits [63:42] = edge count, bits [41:0] = sum(ew) in 2^-32 fixed pt

__global__ __launch_bounds__(256) void init_node(unsigned long long* packed, int N) {
    int i = blockIdx.x * 256 + threadIdx.x;
    if (i < N) packed[i] = 0ull;
}

__global__ __launch_bounds__(256) void accum_deg_hist(const int* __restrict__ dst,
                                                      const float* __restrict__ ew,
                                                      unsigned long long* packed, int E) {
    int e = blockIdx.x * 256 + threadIdx.x;
    if (e < E) {
        int d = dst[e];
        unsigned long long add =
            (1ull << 42) + (unsigned long long)(ew[e] * 4294967296.0f);
        atomicAdd(&packed[d], add);
    }
}

#define SCAN_TILE 2048

// exclusive scan of counts; also computes dinv = rsqrt(1 + deg) per node
__global__ __launch_bounds__(256) void scan1(const unsigned long long* __restrict__ packed,
                                             int* __restrict__ rowptr,
                                             float* __restrict__ dinv,
                                             int* __restrict__ bsums, int N) {
    __shared__ int tmp[256];
    int t = threadIdx.x;
    int base = blockIdx.x * SCAN_TILE + t * 8;
    int v[8], s = 0;
#pragma unroll
    for (int j = 0; j < 8; ++j) {
        int idx = base + j;
        if (idx < N) {
            unsigned long long pv = packed[idx];
            v[j] = (int)(pv >> 42);
            dinv[idx] = rsqrtf(1.0f + (float)(pv & DEG_MASK) * (1.0f / 4294967296.0f));
        } else v[j] = 0;
        s += v[j];
    }
    tmp[t] = s;
    __syncthreads();
#pragma unroll
    for (int off = 1; off < 256; off <<= 1) {
        int u = (t >= off) ? tmp[t - off] : 0;
        __syncthreads();
        tmp[t] += u;
        __syncthreads();
    }
    int run = tmp[t] - s;
#pragma unroll
    for (int j = 0; j < 8; ++j) {
        if (base + j < N) rowptr[base + j] = run;
        run += v[j];
    }
    if (t == 255) bsums[blockIdx.x] = tmp[255];
}

__global__ __launch_bounds__(256) void scan2(int* bsums, int* rowptr, int NB, int N, int E) {
    __shared__ int tmp[256];
    int t = threadIdx.x;
    int v = (t < NB) ? bsums[t] : 0;
    tmp[t] = v;
    __syncthreads();
#pragma unroll
    for (int off = 1; off < 256; off <<= 1) {
        int u = (t >= off) ? tmp[t - off] : 0;
        __syncthreads();
        tmp[t] += u;
        __syncthreads();
    }
    if (t < NB) bsums[t] = tmp[t] - v;
    if (t == 0) rowptr[N] = E;
}

// writes final rowptr AND initializes cursor = rowptr
__global__ __launch_bounds__(256) void scan3(int* rowptr, int* cursor,
                                             const int* __restrict__ bsums, int N) {
    int base = blockIdx.x * SCAN_TILE + threadIdx.x * 8;
    int off = bsums[blockIdx.x];
#pragma unroll
    for (int j = 0; j < 8; ++j)
        if (base + j < N) {
            int v = rowptr[base + j] + off;
            rowptr[base + j] = v;
            cursor[base + j] = v;
        }
}

// single atomic per edge; val = dinv[src]*ew (dinv[dst] applied in gather)
__global__ __launch_bounds__(256) void fill_csr(const int* __restrict__ src,
                                                const int* __restrict__ dst,
                                                const float* __restrict__ ew,
                                                const float* __restrict__ dinv,
                                                int* __restrict__ cursor,
                                                int2* __restrict__ cv, int E) {
    int e = blockIdx.x * 256 + threadIdx.x;
    if (e < E) {
        int d = dst[e], s = src[e];
        int pos = atomicAdd(&cursor[d], 1);
        float v = dinv[s] * ew[e];
        cv[pos] = make_int2(s, __float_as_int(v));
    }
}

// --------- W[K][N] fp32 -> fp16 transposed [N][Kpad] (zero-padded K) -------
__global__ __launch_bounds__(256) void tohalf_w(const float* __restrict__ W,
                                                __half* __restrict__ WT,
                                                int K, int N, int Kpad) {
    int idx = blockIdx.x * 256 + threadIdx.x;
    int total = N * Kpad;
    if (idx >= total) return;
    int n = idx / Kpad, k = idx % Kpad;
    float v = (k < K) ? W[(size_t)k * N + n] : 0.0f;
    WT[idx] = __float2half(v);
}

// ------- GEMM1: C[M,BN](fp16) = A[M,K](fp32) @ BT^T, fused A-convert -------
// A prefetch distance 2 (two named reg sets), B depth-1 DMA. Per-iteration
// FIFO (exact for EVERY thread): [A(s+1) x4][B(s+1) x2][A(s+2) x4]
//   vmcnt(6) = A(s+1) landed, vmcnt(4) = B(s+1) landed, A(s+2) in flight.
// Requires K even (float2 tail clamp never straddles); enforced by caller.
template <int BM, int BN, int WARPS_M, int WARPS_N, int NT>
__global__ __launch_bounds__(NT) void gemm_f32a(const float* __restrict__ Ax,
                                                const __half* __restrict__ BT,
                                                __half* __restrict__ C,
                                                int M, int K, int Kpad) {
    const int WM = BM / WARPS_M, WN = BN / WARPS_N;
    const int FM = WM / 16, FN = WN / 16;
    const int ACH = BM * 4;              // A chunks (8 halfs each)
    const int BCH = BN * 4;              // B chunks
    static_assert(ACH == NT, "1 A-chunk per thread");
    static_assert(BCH == 2 * NT, "2 B-chunks per thread");
    __shared__ __align__(16) __half lds[2][(ACH + BCH) * 8];

    int tid = threadIdx.x;
    int lane = tid & 63;
    int w = tid >> 6;
    int wr = w / WARPS_N, wc = w % WARPS_N;
    int bm = blockIdx.x * BM;
    int lrow = lane & 15;
    int lslot = lane >> 4;

    // A chunk geometry (1 per thread)
    int arow = tid >> 2, ap = tid & 3;
    int aslot = ap ^ ((arow >> 1) & 3);
    int agrow = bm + arow; if (agrow >= M) agrow = M - 1;
    const float* abase = Ax + (size_t)agrow * K;

    // B source pointers (2 per thread)
    const __half* bsrc[2];
#pragma unroll
    for (int i = 0; i < 2; ++i) {
        int c = tid + i * NT;
        int row = c >> 2, p = c & 3;
        bsrc[i] = BT + (size_t)row * Kpad + (size_t)((p ^ ((row >> 1) & 3)) * 8);
    }

    f32x4 acc[FM][FN];
#pragma unroll
    for (int m = 0; m < FM; ++m)
#pragma unroll
        for (int n = 0; n < FN; ++n) acc[m][n] = (f32x4){0.f, 0.f, 0.f, 0.f};

    float2 arA[4], arB[4];  // two named in-flight A sets (static indexing)

    // EXACTLY 4 float2 loads regardless of K-tail: clamp address (K even,
    // so K-2 is a valid aligned float2), zero out-of-range via selects.
    auto loadA = [&](int s, float2 (&ar)[4]) {
        int gk = s * 32 + aslot * 8;
#pragma unroll
        for (int j = 0; j < 4; ++j) {
            int kk = gk + 2 * j;
            int ck = (kk <= K - 2) ? kk : (K - 2);
            float2 v = *(const float2*)(abase + ck);
            if (kk >= K) { v.x = 0.0f; v.y = 0.0f; }
            ar[j] = v;
        }
    };
    auto writeA = [&](int buf, float2 (&ar)[4]) {
        union { __half2 h[4]; uint4 u; } pk;
#pragma unroll
        for (int j = 0; j < 4; ++j) pk.h[j] = __floats2half2_rn(ar[j].x, ar[j].y);
        *(uint4*)&lds[buf][(size_t)tid * 8] = pk.u;
    };
    auto stageB = [&](int buf) {
#pragma unroll
        for (int i = 0; i < 2; ++i) {
            async_copy16(bsrc[i], &lds[buf][(size_t)((tid & ~63) + (i + 1) * NT) * 8]);
            bsrc[i] += 32;
        }
    };

    auto compute = [&](int buf) {
        f16x8 af[FM], bf[FN];
#pragma unroll
        for (int m = 0; m < FM; ++m) {
            int row = wr * WM + m * 16 + lrow;
            int p = lslot ^ ((row >> 1) & 3);
            af[m] = *(const f16x8*)&lds[buf][(size_t)(row * 4 + p) * 8];
        }
#pragma unroll
        for (int n = 0; n < FN; ++n) {
            int row = wc * WN + n * 16 + lrow;
            int p = lslot ^ ((row >> 1) & 3);
            bf[n] = *(const f16x8*)&lds[buf][(size_t)(ACH + row * 4 + p) * 8];
        }
#pragma unroll
        for (int m = 0; m < FM; ++m)
#pragma unroll
            for (int n = 0; n < FN; ++n)
                acc[m][n] = __builtin_amdgcn_mfma_f32_16x16x32_f16(af[m], bf[n], acc[m][n], 0, 0, 0);
    };

    const int nsteps = Kpad / 32;   // 13 for K=394
    // prologue: FIFO [A0 x4][B0 x2][A1 x4] = 10 outstanding (exact)
    loadA(0, arA);
    stageB(0);
    loadA(1, arB);
    asm volatile("s_waitcnt vmcnt(6)" ::: "memory");   // A0 landed
    writeA(0, arA);
    asm volatile("s_waitcnt vmcnt(4)" ::: "memory");   // B0 landed (A1 flying)
    asm volatile("s_waitcnt lgkmcnt(0)" ::: "memory");
    __builtin_amdgcn_s_barrier();

    // steady state, manual 2x unroll for static reg-set selection.
    // iteration body: wset holds A(s+1); load A(s+2) into lset.
    auto iter = [&](int s, float2 (&wset)[4], float2 (&lset)[4]) {
        bool m1 = (s + 1 < nsteps), m2 = (s + 2 < nsteps);
        if (m1) stageB((s + 1) & 1);
        if (m2) loadA(s + 2, lset);
        compute(s & 1);
        if (m1) {
            if (m2) asm volatile("s_waitcnt vmcnt(6)" ::: "memory");
            else    asm volatile("s_waitcnt vmcnt(2)" ::: "memory");
            writeA((s + 1) & 1, wset);
            if (m2) asm volatile("s_waitcnt vmcnt(4)" ::: "memory");
            else    asm volatile("s_waitcnt vmcnt(0)" ::: "memory");
            asm volatile("s_waitcnt lgkmcnt(0)" ::: "memory");
        }
        __builtin_amdgcn_s_barrier();
    };
    int s = 0;
    for (; s + 1 < nsteps; s += 2) {
        iter(s, arB, arA);      // even s: write arB (A s+1), load into arA
        iter(s + 1, arA, arB);  // odd  s: write arA, load into arB
    }
    if (s < nsteps) iter(s, arB, arA);  // odd-nsteps tail (compute only)

    // ---- epilogue: per-wave LDS bounce -> 16B coalesced C stores ----
    __syncthreads();
    {
        const int LW = WN + 8;
        __half* tile = (__half*)lds + (size_t)w * 16 * LW;
        const int CPR = WN / 8;
        const int CHT = (16 * CPR) / 64;
#pragma unroll
        for (int m = 0; m < FM; ++m) {
            int rb = bm + wr * WM + m * 16;
#pragma unroll
            for (int n = 0; n < FN; ++n)
#pragma unroll
                for (int i = 0; i < 4; ++i)
                    tile[((lane >> 4) * 4 + i) * LW + n * 16 + (lane & 15)] =
                        __float2half(acc[m][n][i]);
#pragma unroll
            for (int c = 0; c < CHT; ++c) {
                int ch = lane + c * 64;
                int r = ch / CPR, cc = ch % CPR;
                uint4 v = *(uint4*)&tile[r * LW + cc * 8];
                int grow = rb + r;
                if (grow < M)
                    *(uint4*)&C[(size_t)grow * BN + wc * WN + cc * 8] = v;
            }
        }
    }
}

// ---------------- GEMM2: fp16 A, all-global_load_lds staging ---------------
template <int BM, int BN, int WARPS_M, int WARPS_N, int NT>
__global__ __launch_bounds__(NT) void gemm_f16(const __half* __restrict__ Ah,
                                               const __half* __restrict__ BT,
                                               __half* __restrict__ C,
                                               int M, int Kpad) {
    const int WM = BM / WARPS_M, WN = BN / WARPS_N;
    const int FM = WM / 16, FN = WN / 16;
    const int ACH = BM * 4;
    const int BCH = BN * 4;
    const int TOTCH = ACH + BCH;
    const int CH = TOTCH / NT;
    static_assert(CH == 3, "vmcnt(3) hardcoded below");
    __shared__ __align__(16) __half lds[2][TOTCH * 8];

    int tid = threadIdx.x;
    int lane = tid & 63;
    int w = tid >> 6;
    int wr = w / WARPS_N, wc = w % WARPS_N;
    int bm = blockIdx.x * BM;
    int lrow = lane & 15;
    int lslot = lane >> 4;

    const __half* srcp[CH];
#pragma unroll
    for (int i = 0; i < CH; ++i) {
        int ch = tid + i * NT;
        if (ch < ACH) {
            int c = ch, row = c >> 2;
            int grow = bm + row;
            if (grow >= M) grow = M - 1;
            srcp[i] = Ah + (size_t)grow * Kpad + (size_t)(((c & 3) ^ ((row >> 1) & 3)) * 8);
        } else {
            int c = ch - ACH, row = c >> 2;
            srcp[i] = BT + (size_t)row * Kpad + (size_t)(((c & 3) ^ ((row >> 1) & 3)) * 8);
        }
    }

    f32x4 acc[FM][FN];
#pragma unroll
    for (int m = 0; m < FM; ++m)
#pragma unroll
        for (int n = 0; n < FN; ++n) acc[m][n] = (f32x4){0.f, 0.f, 0.f, 0.f};

    auto stage = [&](int buf) {
#pragma unroll
        for (int i = 0; i < CH; ++i) {
            async_copy16(srcp[i], &lds[buf][(size_t)((tid & ~63) + i * NT) * 8]);
            srcp[i] += 32;
        }
    };

    auto compute = [&](int buf) {
        f16x8 af[FM], bf[FN];
#pragma unroll
        for (int m = 0; m < FM; ++m) {
            int row = wr * WM + m * 16 + lrow;
            int p = lslot ^ ((row >> 1) & 3);
            af[m] = *(const f16x8*)&lds[buf][(size_t)(row * 4 + p) * 8];
        }
#pragma unroll
        for (int n = 0; n < FN; ++n) {
            int row = wc * WN + n * 16 + lrow;
            int p = lslot ^ ((row >> 1) & 3);
            bf[n] = *(const f16x8*)&lds[buf][(size_t)(ACH + row * 4 + p) * 8];
        }
#pragma unroll
        for (int m = 0; m < FM; ++m)
#pragma unroll
            for (int n = 0; n < FN; ++n)
                acc[m][n] = __builtin_amdgcn_mfma_f32_16x16x32_f16(af[m], bf[n], acc[m][n], 0, 0, 0);
    };

    const int nsteps = Kpad / 32;
    stage(0);
    for (int s = 0; s < nsteps; ++s) {
        if (s + 1 < nsteps) {
            stage((s + 1) & 1);
            asm volatile("s_waitcnt vmcnt(3)" ::: "memory");
        } else {
            asm volatile("s_waitcnt vmcnt(0)" ::: "memory");
        }
        __builtin_amdgcn_s_barrier();
        compute(s & 1);
        __builtin_amdgcn_s_barrier();
    }

    __syncthreads();
    {
        const int LW = WN + 8;
        __half* tile = (__half*)lds + (size_t)w * 16 * LW;
        const int CPR = WN / 8;
        const int CHT = (16 * CPR) / 64;
#pragma unroll
        for (int m = 0; m < FM; ++m) {
            int rb = bm + wr * WM + m * 16;
#pragma unroll
            for (int n = 0; n < FN; ++n)
#pragma unroll
                for (int i = 0; i < 4; ++i)
                    tile[((lane >> 4) * 4 + i) * LW + n * 16 + (lane & 15)] =
                        __float2half(acc[m][n][i]);
#pragma unroll
            for (int c = 0; c < CHT; ++c) {
                int ch = lane + c * 64;
                int r = ch / CPR, cc = ch % CPR;
                uint4 v = *(uint4*)&tile[r * LW + cc * 8];
                int grow = rb + r;
                if (grow < M)
                    *(uint4*)&C[(size_t)grow * BN + wc * WN + cc * 8] = v;
            }
        }
    }
}

// ---- gather aggregation (fp16 features, fp32 accum, 4x unrolled) ----------
// out[d] = bias + dinv[d]*( dinv[d]*xw[d] + sum_p val[p]*xw[col[p]] )  (; relu)
// where val[p] = dinv[src]*ew  (dinv[d] factored out of the sum)
template <int F, int LPN, int RELU, typename OutT>
__global__ __launch_bounds__(256) void gatherh(const int* __restrict__ rowptr,
                                               const int2* __restrict__ cv,
                                               const __half* __restrict__ xw,
                                               const float* __restrict__ dinv,
                                               const float* __restrict__ bias,
                                               OutT* __restrict__ out, int N) {
    const int NPB = 256 / LPN;
    int d = blockIdx.x * NPB + threadIdx.x / LPN;
    if (d >= N) return;
    int lane = threadIdx.x % LPN;

    float di = dinv[d];
    uint2 raw = *(const uint2*)(xw + (size_t)d * F + lane * 4);
    float2 u0 = __half22float2(*(__half2*)&raw.x);
    float2 u1 = __half22float2(*(__half2*)&raw.y);
    float a0 = di * u0.x, a1 = di * u0.y, a2 = di * u1.x, a3 = di * u1.y;
    float b0 = 0.f, b1 = 0.f, b2 = 0.f, b3 = 0.f;

    int p = rowptr[d], p1 = rowptr[d + 1];
    for (; p + 4 <= p1; p += 4) {
        int2 e0 = cv[p], e1 = cv[p + 1], e2 = cv[p + 2], e3 = cv[p + 3];
        uint2 r0 = *(const uint2*)(xw + (size_t)e0.x * F + lane * 4);
        uint2 r1 = *(const uint2*)(xw + (size_t)e1.x * F + lane * 4);
        uint2 r2 = *(const uint2*)(xw + (size_t)e2.x * F + lane * 4);
        uint2 r3 = *(const uint2*)(xw + (size_t)e3.x * F + lane * 4);
        float w0 = __int_as_float(e0.y), w1 = __int_as_float(e1.y);
        float w2 = __int_as_float(e2.y), w3 = __int_as_float(e3.y);
        {
            float2 v0 = __half22float2(*(__half2*)&r0.x);
            float2 v1 = __half22float2(*(__half2*)&r0.y);
            a0 = fmaf(w0, v0.x, a0); a1 = fmaf(w0, v0.y, a1);
            a2 = fmaf(w0, v1.x, a2); a3 = fmaf(w0, v1.y, a3);
        }
        {
            float2 v0 = __half22float2(*(__half2*)&r1.x);
            float2 v1 = __half22float2(*(__half2*)&r1.y);
            b0 = fmaf(w1, v0.x, b0); b1 = fmaf(w1, v0.y, b1);
            b2 = fmaf(w1, v1.x, b2); b3 = fmaf(w1, v1.y, b3);
        }
        {
            float2 v0 = __half22float2(*(__half2*)&r2.x);
            float2 v1 = __half22float2(*(__half2*)&r2.y);
            a0 = fmaf(w2, v0.x, a0); a1 = fmaf(w2, v0.y, a1);
            a2 = fmaf(w2, v1.x, a2); a3 = fmaf(w2, v1.y, a3);
        }
        {
            float2 v0 = __half22float2(*(__half2*)&r3.x);
            float2 v1 = __half22float2(*(__half2*)&r3.y);
            b0 = fmaf(w3, v0.x, b0); b1 = fmaf(w3, v0.y, b1);
            b2 = fmaf(w3, v1.x, b2); b3 = fmaf(w3, v1.y, b3);
        }
    }
    for (; p < p1; ++p) {
        int2 e = cv[p];
        float wv = __int_as_float(e.y);
        uint2 rv = *(const uint2*)(xw + (size_t)e.x * F + lane * 4);
        float2 v0 = __half22float2(*(__half2*)&rv.x);
        float2 v1 = __half22float2(*(__half2*)&rv.y);
        a0 = fmaf(wv, v0.x, a0); a1 = fmaf(wv, v0.y, a1);
        a2 = fmaf(wv, v1.x, a2); a3 = fmaf(wv, v1.y, a3);
    }
    a0 += b0; a1 += b1; a2 += b2; a3 += b3;
    a0 *= di; a1 *= di; a2 *= di; a3 *= di;   // apply dinv[d] once

    float4 bb = *(const float4*)&bias[lane * 4];
    a0 += bb.x; a1 += bb.y; a2 += bb.z; a3 += bb.w;
    if (RELU) {
        a0 = fmaxf(a0, 0.f); a1 = fmaxf(a1, 0.f);
        a2 = fmaxf(a2, 0.f); a3 = fmaxf(a3, 0.f);
    }
    if constexpr (std::is_same_v<OutT, float>) {
        *(float4*)&out[(size_t)d * F + lane * 4] = make_float4(a0, a1, a2, a3);
    } else {
        __half2 h0 = __floats2half2_rn(a0, a1);
        __half2 h1 = __floats2half2_rn(a2, a3);
        uint2 packed;
        packed.x = *(uint*)&h0;
        packed.y = *(uint*)&h1;
        *(uint2*)&out[(size_t)d * F + lane * 4] = packed;
    }
}

extern "C" void kernel_launch(void* const* d_in, const int* in_sizes, int n_in,
                              void* d_out, int out_size, void* d_ws, size_t ws_size,
                              hipStream_t stream) {
    const float* x  = (const float*)d_in[0];
    const int*   ei = (const int*)d_in[1];
    const float* ew = (const float*)d_in[2];
    const float* W1 = (const float*)d_in[3];
    const float* b1 = (const float*)d_in[4];
    const float* W2 = (const float*)d_in[5];
    const float* b2 = (const float*)d_in[6];
    float* out = (float*)d_out;

    const int H    = in_sizes[4];            // 256
    const int Fout = in_sizes[6];            // 64
    const int Fin  = in_sizes[3] / H;        // 394 (even — required by gemm_f32a)
    const int N    = in_sizes[0] / Fin;      // 100000
    const int E    = in_sizes[2];            // 1600000

    const int Kpad1 = (Fin + 31) / 32 * 32;  // 416
    const int Kpad2 = (H + 31) / 32 * 32;    // 256

    const int* src = ei;
    const int* dst = ei + E;

    // workspace layout (all sections 16B aligned)
    unsigned long long* packed = (unsigned long long*)d_ws;  // N
    float* dinv   = (float*)(packed + N);         // N
    int*   rowptr = (int*)(dinv + N);             // N+4
    int*   cursor = rowptr + N + 4;               // N+4
    int*   bsums  = cursor + N + 4;               // 256
    int2*  cv     = (int2*)(bsums + 256);         // E int2 (col,val)
    __half* bufA  = (__half*)(cv + E);            // N*H (xw1, later xw2)
    __half* bufB  = bufA + (size_t)N * H;         // N*H (h)
    __half* wt1   = bufB + (size_t)N * H;         // H*Kpad1
    __half* wt2   = wt1 + (size_t)H * Kpad1;      // Fout*Kpad2

    const int NB = (N + SCAN_TILE - 1) / SCAN_TILE;

    // 1. degrees + histogram: ONE packed 64-bit atomic per edge
    init_node<<<(N + 255) / 256, 256, 0, stream>>>(packed, N);
    accum_deg_hist<<<(E + 255) / 256, 256, 0, stream>>>(dst, ew, packed, E);

    // 2. CSR build (dinv fused into scan1; cursor-based fill)
    scan1<<<NB, 256, 0, stream>>>(packed, rowptr, dinv, bsums, N);
    scan2<<<1, 256, 0, stream>>>(bsums, rowptr, NB, N, E);
    scan3<<<NB, 256, 0, stream>>>(rowptr, cursor, bsums, N);
    fill_csr<<<(E + 255) / 256, 256, 0, stream>>>(src, dst, ew, dinv, cursor, cv, E);

    // 3. weight conversions (x conversion fused into GEMM1)
    tohalf_w<<<(H * Kpad1 + 255) / 256, 256, 0, stream>>>(W1, wt1, Fin, H, Kpad1);
    tohalf_w<<<(Fout * Kpad2 + 255) / 256, 256, 0, stream>>>(W2, wt2, H, Fout, Kpad2);

    // 4. xw1 = x @ W1   [N,394](fp32)@[394,256] -> fp16 (A prefetch depth 2)
    gemm_f32a<128, 256, 2, 4, 512><<<(N + 127) / 128, 512, 0, stream>>>(
        x, wt1, bufA, N, Fin, Kpad1);

    // 5. h = relu(gather + bias) -> fp16
    gatherh<256, 64, 1, __half><<<(N + 3) / 4, 256, 0, stream>>>(
        rowptr, cv, bufA, dinv, b1, bufB, N);

    // 6. xw2 = h @ W2   [N,256]@[256,64] -> fp16
    gemm_f16<128, 64, 2, 2, 256><<<(N + 127) / 128, 256, 0, stream>>>(bufB, wt2, bufA, N, Kpad2);

    // 7. out = gather + bias -> fp32
    gatherh<64, 16, 0, float><<<(N + 15) / 16, 256, 0, stream>>>(
        rowptr, cv, bufA, dinv, b2, out, N);
}

// Round 16
// 466.637 us; speedup vs baseline: 1.0591x; 1.0591x over previous
//
#include <hip/hip_runtime.h>
#include <hip/hip_bf16.h>
#include <hip/hip_fp16.h>
#include <type_traits>

// ---------------------------------------------------------------------------
// 2-layer GCN. CSR-gather aggregation (fp16 features, fp32 accum, 4x-unrolled
// edge loop; dinv[d] factored out of edge vals -> applied once per node).
// Preprocessing: ONE 64-bit packed atomic per edge; dinv fused into scan1;
// cursor-based CSR fill.
// GEMM1: fp32 A, fused convert, depth-1 issue-early schedule (R13 config —
// depth-2 prefetch measured as a 27us regression in R15). Safe because every
// iteration ends with a full vmcnt(0) drain before the barrier.
// GEMM2: fp16 A via global_load_lds (counted vmcnt(3)).
// Both: fp16 MFMA fp32-accum, double-buffered LDS, LDS-bounce epilogue.
// ---------------------------------------------------------------------------

typedef _Float16 f16x8 __attribute__((ext_vector_type(8)));
typedef float f32x4 __attribute__((ext_vector_type(4)));

#define DEG_MASK ((1ull << 42) - 1)

__device__ inline void async_copy16(const void* g, void* l) {
    __builtin_amdgcn_global_load_lds(
        (const __attribute__((address_space(1))) void*)g,
        (__attribute__((address_space(3))) void*)l, 16, 0, 0);
}

// ------------------------- graph preprocessing -----------------------------
// packed[i]: bits [63:42] = edge count, bits [41:0] = sum(ew) in 2^-32 fixed pt

__global__ __launch_bounds__(256) void init_node(unsigned long long* packed, int N) {
    int i = blockIdx.x * 256 + threadIdx.x;
    if (i < N) packed[i] = 0ull;
}

__global__ __launch_bounds__(256) void accum_deg_hist(const int* __restrict__ dst,
                                                      const float* __restrict__ ew,
                                                      unsigned long long* packed, int E) {
    int e = blockIdx.x * 256 + threadIdx.x;
    if (e < E) {
        int d = dst[e];
        unsigned long long add =
            (1ull << 42) + (unsigned long long)(ew[e] * 4294967296.0f);
        atomicAdd(&packed[d], add);
    }
}

#define SCAN_TILE 2048

// exclusive scan of counts; also computes dinv = rsqrt(1 + deg) per node
__global__ __launch_bounds__(256) void scan1(const unsigned long long* __restrict__ packed,
                                             int* __restrict__ rowptr,
                                             float* __restrict__ dinv,
                                             int* __restrict__ bsums, int N) {
    __shared__ int tmp[256];
    int t = threadIdx.x;
    int base = blockIdx.x * SCAN_TILE + t * 8;
    int v[8], s = 0;
#pragma unroll
    for (int j = 0; j < 8; ++j) {
        int idx = base + j;
        if (idx < N) {
            unsigned long long pv = packed[idx];
            v[j] = (int)(pv >> 42);
            dinv[idx] = rsqrtf(1.0f + (float)(pv & DEG_MASK) * (1.0f / 4294967296.0f));
        } else v[j] = 0;
        s += v[j];
    }
    tmp[t] = s;
    __syncthreads();
#pragma unroll
    for (int off = 1; off < 256; off <<= 1) {
        int u = (t >= off) ? tmp[t - off] : 0;
        __syncthreads();
        tmp[t] += u;
        __syncthreads();
    }
    int run = tmp[t] - s;
#pragma unroll
    for (int j = 0; j < 8; ++j) {
        if (base + j < N) rowptr[base + j] = run;
        run += v[j];
    }
    if (t == 255) bsums[blockIdx.x] = tmp[255];
}

__global__ __launch_bounds__(256) void scan2(int* bsums, int* rowptr, int NB, int N, int E) {
    __shared__ int tmp[256];
    int t = threadIdx.x;
    int v = (t < NB) ? bsums[t] : 0;
    tmp[t] = v;
    __syncthreads();
#pragma unroll
    for (int off = 1; off < 256; off <<= 1) {
        int u = (t >= off) ? tmp[t - off] : 0;
        __syncthreads();
        tmp[t] += u;
        __syncthreads();
    }
    if (t < NB) bsums[t] = tmp[t] - v;
    if (t == 0) rowptr[N] = E;
}

// writes final rowptr AND initializes cursor = rowptr
__global__ __launch_bounds__(256) void scan3(int* rowptr, int* cursor,
                                             const int* __restrict__ bsums, int N) {
    int base = blockIdx.x * SCAN_TILE + threadIdx.x * 8;
    int off = bsums[blockIdx.x];
#pragma unroll
    for (int j = 0; j < 8; ++j)
        if (base + j < N) {
            int v = rowptr[base + j] + off;
            rowptr[base + j] = v;
            cursor[base + j] = v;
        }
}

// single atomic per edge; val = dinv[src]*ew (dinv[dst] applied in gather)
__global__ __launch_bounds__(256) void fill_csr(const int* __restrict__ src,
                                                const int* __restrict__ dst,
                                                const float* __restrict__ ew,
                                                const float* __restrict__ dinv,
                                                int* __restrict__ cursor,
                                                int2* __restrict__ cv, int E) {
    int e = blockIdx.x * 256 + threadIdx.x;
    if (e < E) {
        int d = dst[e], s = src[e];
        int pos = atomicAdd(&cursor[d], 1);
        float v = dinv[s] * ew[e];
        cv[pos] = make_int2(s, __float_as_int(v));
    }
}

// --------- W[K][N] fp32 -> fp16 transposed [N][Kpad] (zero-padded K) -------
__global__ __launch_bounds__(256) void tohalf_w(const float* __restrict__ W,
                                                __half* __restrict__ WT,
                                                int K, int N, int Kpad) {
    int idx = blockIdx.x * 256 + threadIdx.x;
    int total = N * Kpad;
    if (idx >= total) return;
    int n = idx / Kpad, k = idx % Kpad;
    float v = (k < K) ? W[(size_t)k * N + n] : 0.0f;
    WT[idx] = __float2half(v);
}

// ------- GEMM1: C[M,BN](fp16) = A[M,K](fp32) @ BT^T, fused A-convert -------
// Depth-1 issue-early: loads for s+1 before compute(s); vmcnt(2) = A landed
// (FIFO [A x4][B x2]), convert+write, then FULL vmcnt(0) drain + lgkmcnt(0)
// before the single per-step barrier (correct for variable tail loads).
template <int BM, int BN, int WARPS_M, int WARPS_N, int NT>
__global__ __launch_bounds__(NT) void gemm_f32a(const float* __restrict__ Ax,
                                                const __half* __restrict__ BT,
                                                __half* __restrict__ C,
                                                int M, int K, int Kpad) {
    const int WM = BM / WARPS_M, WN = BN / WARPS_N;
    const int FM = WM / 16, FN = WN / 16;
    const int ACH = BM * 4;              // A chunks (8 halfs each)
    const int BCH = BN * 4;              // B chunks
    static_assert(ACH == NT, "1 A-chunk per thread");
    static_assert(BCH == 2 * NT, "2 B-chunks per thread");
    __shared__ __align__(16) __half lds[2][(ACH + BCH) * 8];

    int tid = threadIdx.x;
    int lane = tid & 63;
    int w = tid >> 6;
    int wr = w / WARPS_N, wc = w % WARPS_N;
    int bm = blockIdx.x * BM;
    int lrow = lane & 15;
    int lslot = lane >> 4;

    // A chunk geometry (1 per thread)
    int arow = tid >> 2, ap = tid & 3;
    int aslot = ap ^ ((arow >> 1) & 3);
    int agrow = bm + arow; if (agrow >= M) agrow = M - 1;
    const float* abase = Ax + (size_t)agrow * K;

    // B source pointers (2 per thread)
    const __half* bsrc[2];
#pragma unroll
    for (int i = 0; i < 2; ++i) {
        int c = tid + i * NT;
        int row = c >> 2, p = c & 3;
        bsrc[i] = BT + (size_t)row * Kpad + (size_t)((p ^ ((row >> 1) & 3)) * 8);
    }

    f32x4 acc[FM][FN];
#pragma unroll
    for (int m = 0; m < FM; ++m)
#pragma unroll
        for (int n = 0; n < FN; ++n) acc[m][n] = (f32x4){0.f, 0.f, 0.f, 0.f};

    float2 ar[4];
    auto loadA = [&](int s) {
        int gk = s * 32 + aslot * 8;
        if (gk + 8 <= K) {
            const float* p = abase + gk;  // 8B-aligned always
            ar[0] = *(const float2*)p;
            ar[1] = *(const float2*)(p + 2);
            ar[2] = *(const float2*)(p + 4);
            ar[3] = *(const float2*)(p + 6);
        } else {
            float t[8];
#pragma unroll
            for (int j = 0; j < 8; ++j) t[j] = (gk + j < K) ? abase[gk + j] : 0.0f;
            ar[0] = make_float2(t[0], t[1]);
            ar[1] = make_float2(t[2], t[3]);
            ar[2] = make_float2(t[4], t[5]);
            ar[3] = make_float2(t[6], t[7]);
        }
    };
    auto writeA = [&](int buf) {
        union { __half2 h[4]; uint4 u; } pk;
#pragma unroll
        for (int j = 0; j < 4; ++j) pk.h[j] = __floats2half2_rn(ar[j].x, ar[j].y);
        *(uint4*)&lds[buf][(size_t)tid * 8] = pk.u;
    };
    auto stageB = [&](int buf) {
#pragma unroll
        for (int i = 0; i < 2; ++i) {
            async_copy16(bsrc[i], &lds[buf][(size_t)((tid & ~63) + (i + 1) * NT) * 8]);
            bsrc[i] += 32;
        }
    };

    auto compute = [&](int buf) {
        f16x8 af[FM], bf[FN];
#pragma unroll
        for (int m = 0; m < FM; ++m) {
            int row = wr * WM + m * 16 + lrow;
            int p = lslot ^ ((row >> 1) & 3);
            af[m] = *(const f16x8*)&lds[buf][(size_t)(row * 4 + p) * 8];
        }
#pragma unroll
        for (int n = 0; n < FN; ++n) {
            int row = wc * WN + n * 16 + lrow;
            int p = lslot ^ ((row >> 1) & 3);
            bf[n] = *(const f16x8*)&lds[buf][(size_t)(ACH + row * 4 + p) * 8];
        }
#pragma unroll
        for (int m = 0; m < FM; ++m)
#pragma unroll
            for (int n = 0; n < FN; ++n)
                acc[m][n] = __builtin_amdgcn_mfma_f32_16x16x32_f16(af[m], bf[n], acc[m][n], 0, 0, 0);
    };

    const int nsteps = Kpad / 32;
    // prologue: fill buf 0
    loadA(0);                            // 4 loads issued first (oldest)
    stageB(0);                           // 2 DMAs after
    asm volatile("s_waitcnt vmcnt(2)" ::: "memory");   // A regs landed
    writeA(0);
    asm volatile("s_waitcnt vmcnt(0) lgkmcnt(0)" ::: "memory");
    __builtin_amdgcn_s_barrier();
    for (int s = 0; s < nsteps; ++s) {
        bool more = (s + 1 < nsteps);
        if (more) { loadA(s + 1); stageB((s + 1) & 1); }
        compute(s & 1);
        if (more) {
            asm volatile("s_waitcnt vmcnt(2)" ::: "memory");
            writeA((s + 1) & 1);
            asm volatile("s_waitcnt vmcnt(0) lgkmcnt(0)" ::: "memory");
        }
        __builtin_amdgcn_s_barrier();
    }

    // ---- epilogue: per-wave LDS bounce -> 16B coalesced C stores ----
    __syncthreads();
    {
        const int LW = WN + 8;
        __half* tile = (__half*)lds + (size_t)w * 16 * LW;
        const int CPR = WN / 8;
        const int CHT = (16 * CPR) / 64;
#pragma unroll
        for (int m = 0; m < FM; ++m) {
            int rb = bm + wr * WM + m * 16;
#pragma unroll
            for (int n = 0; n < FN; ++n)
#pragma unroll
                for (int i = 0; i < 4; ++i)
                    tile[((lane >> 4) * 4 + i) * LW + n * 16 + (lane & 15)] =
                        __float2half(acc[m][n][i]);
#pragma unroll
            for (int c = 0; c < CHT; ++c) {
                int ch = lane + c * 64;
                int r = ch / CPR, cc = ch % CPR;
                uint4 v = *(uint4*)&tile[r * LW + cc * 8];
                int grow = rb + r;
                if (grow < M)
                    *(uint4*)&C[(size_t)grow * BN + wc * WN + cc * 8] = v;
            }
        }
    }
}

// ---------------- GEMM2: fp16 A, all-global_load_lds staging ---------------
template <int BM, int BN, int WARPS_M, int WARPS_N, int NT>
__global__ __launch_bounds__(NT) void gemm_f16(const __half* __restrict__ Ah,
                                               const __half* __restrict__ BT,
                                               __half* __restrict__ C,
                                               int M, int Kpad) {
    const int WM = BM / WARPS_M, WN = BN / WARPS_N;
    const int FM = WM / 16, FN = WN / 16;
    const int ACH = BM * 4;
    const int BCH = BN * 4;
    const int TOTCH = ACH + BCH;
    const int CH = TOTCH / NT;
    static_assert(CH == 3, "vmcnt(3) hardcoded below");
    __shared__ __align__(16) __half lds[2][TOTCH * 8];

    int tid = threadIdx.x;
    int lane = tid & 63;
    int w = tid >> 6;
    int wr = w / WARPS_N, wc = w % WARPS_N;
    int bm = blockIdx.x * BM;
    int lrow = lane & 15;
    int lslot = lane >> 4;

    const __half* srcp[CH];
#pragma unroll
    for (int i = 0; i < CH; ++i) {
        int ch = tid + i * NT;
        if (ch < ACH) {
            int c = ch, row = c >> 2;
            int grow = bm + row;
            if (grow >= M) grow = M - 1;
            srcp[i] = Ah + (size_t)grow * Kpad + (size_t)(((c & 3) ^ ((row >> 1) & 3)) * 8);
        } else {
            int c = ch - ACH, row = c >> 2;
            srcp[i] = BT + (size_t)row * Kpad + (size_t)(((c & 3) ^ ((row >> 1) & 3)) * 8);
        }
    }

    f32x4 acc[FM][FN];
#pragma unroll
    for (int m = 0; m < FM; ++m)
#pragma unroll
        for (int n = 0; n < FN; ++n) acc[m][n] = (f32x4){0.f, 0.f, 0.f, 0.f};

    auto stage = [&](int buf) {
#pragma unroll
        for (int i = 0; i < CH; ++i) {
            async_copy16(srcp[i], &lds[buf][(size_t)((tid & ~63) + i * NT) * 8]);
            srcp[i] += 32;
        }
    };

    auto compute = [&](int buf) {
        f16x8 af[FM], bf[FN];
#pragma unroll
        for (int m = 0; m < FM; ++m) {
            int row = wr * WM + m * 16 + lrow;
            int p = lslot ^ ((row >> 1) & 3);
            af[m] = *(const f16x8*)&lds[buf][(size_t)(row * 4 + p) * 8];
        }
#pragma unroll
        for (int n = 0; n < FN; ++n) {
            int row = wc * WN + n * 16 + lrow;
            int p = lslot ^ ((row >> 1) & 3);
            bf[n] = *(const f16x8*)&lds[buf][(size_t)(ACH + row * 4 + p) * 8];
        }
#pragma unroll
        for (int m = 0; m < FM; ++m)
#pragma unroll
            for (int n = 0; n < FN; ++n)
                acc[m][n] = __builtin_amdgcn_mfma_f32_16x16x32_f16(af[m], bf[n], acc[m][n], 0, 0, 0);
    };

    const int nsteps = Kpad / 32;
    stage(0);
    for (int s = 0; s < nsteps; ++s) {
        if (s + 1 < nsteps) {
            stage((s + 1) & 1);
            asm volatile("s_waitcnt vmcnt(3)" ::: "memory");
        } else {
            asm volatile("s_waitcnt vmcnt(0)" ::: "memory");
        }
        __builtin_amdgcn_s_barrier();
        compute(s & 1);
        __builtin_amdgcn_s_barrier();
    }

    __syncthreads();
    {
        const int LW = WN + 8;
        __half* tile = (__half*)lds + (size_t)w * 16 * LW;
        const int CPR = WN / 8;
        const int CHT = (16 * CPR) / 64;
#pragma unroll
        for (int m = 0; m < FM; ++m) {
            int rb = bm + wr * WM + m * 16;
#pragma unroll
            for (int n = 0; n < FN; ++n)
#pragma unroll
                for (int i = 0; i < 4; ++i)
                    tile[((lane >> 4) * 4 + i) * LW + n * 16 + (lane & 15)] =
                        __float2half(acc[m][n][i]);
#pragma unroll
            for (int c = 0; c < CHT; ++c) {
                int ch = lane + c * 64;
                int r = ch / CPR, cc = ch % CPR;
                uint4 v = *(uint4*)&tile[r * LW + cc * 8];
                int grow = rb + r;
                if (grow < M)
                    *(uint4*)&C[(size_t)grow * BN + wc * WN + cc * 8] = v;
            }
        }
    }
}

// ---- gather aggregation (fp16 features, fp32 accum, 4x unrolled) ----------
// out[d] = bias + dinv[d]*( dinv[d]*xw[d] + sum_p val[p]*xw[col[p]] )  (; relu)
// where val[p] = dinv[src]*ew  (dinv[d] factored out of the sum)
template <int F, int LPN, int RELU, typename OutT>
__global__ __launch_bounds__(256) void gatherh(const int* __restrict__ rowptr,
                                               const int2* __restrict__ cv,
                                               const __half* __restrict__ xw,
                                               const float* __restrict__ dinv,
                                               const float* __restrict__ bias,
                                               OutT* __restrict__ out, int N) {
    const int NPB = 256 / LPN;
    int d = blockIdx.x * NPB + threadIdx.x / LPN;
    if (d >= N) return;
    int lane = threadIdx.x % LPN;

    float di = dinv[d];
    uint2 raw = *(const uint2*)(xw + (size_t)d * F + lane * 4);
    float2 u0 = __half22float2(*(__half2*)&raw.x);
    float2 u1 = __half22float2(*(__half2*)&raw.y);
    float a0 = di * u0.x, a1 = di * u0.y, a2 = di * u1.x, a3 = di * u1.y;
    float b0 = 0.f, b1 = 0.f, b2 = 0.f, b3 = 0.f;

    int p = rowptr[d], p1 = rowptr[d + 1];
    for (; p + 4 <= p1; p += 4) {
        int2 e0 = cv[p], e1 = cv[p + 1], e2 = cv[p + 2], e3 = cv[p + 3];
        uint2 r0 = *(const uint2*)(xw + (size_t)e0.x * F + lane * 4);
        uint2 r1 = *(const uint2*)(xw + (size_t)e1.x * F + lane * 4);
        uint2 r2 = *(const uint2*)(xw + (size_t)e2.x * F + lane * 4);
        uint2 r3 = *(const uint2*)(xw + (size_t)e3.x * F + lane * 4);
        float w0 = __int_as_float(e0.y), w1 = __int_as_float(e1.y);
        float w2 = __int_as_float(e2.y), w3 = __int_as_float(e3.y);
        {
            float2 v0 = __half22float2(*(__half2*)&r0.x);
            float2 v1 = __half22float2(*(__half2*)&r0.y);
            a0 = fmaf(w0, v0.x, a0); a1 = fmaf(w0, v0.y, a1);
            a2 = fmaf(w0, v1.x, a2); a3 = fmaf(w0, v1.y, a3);
        }
        {
            float2 v0 = __half22float2(*(__half2*)&r1.x);
            float2 v1 = __half22float2(*(__half2*)&r1.y);
            b0 = fmaf(w1, v0.x, b0); b1 = fmaf(w1, v0.y, b1);
            b2 = fmaf(w1, v1.x, b2); b3 = fmaf(w1, v1.y, b3);
        }
        {
            float2 v0 = __half22float2(*(__half2*)&r2.x);
            float2 v1 = __half22float2(*(__half2*)&r2.y);
            a0 = fmaf(w2, v0.x, a0); a1 = fmaf(w2, v0.y, a1);
            a2 = fmaf(w2, v1.x, a2); a3 = fmaf(w2, v1.y, a3);
        }
        {
            float2 v0 = __half22float2(*(__half2*)&r3.x);
            float2 v1 = __half22float2(*(__half2*)&r3.y);
            b0 = fmaf(w3, v0.x, b0); b1 = fmaf(w3, v0.y, b1);
            b2 = fmaf(w3, v1.x, b2); b3 = fmaf(w3, v1.y, b3);
        }
    }
    for (; p < p1; ++p) {
        int2 e = cv[p];
        float wv = __int_as_float(e.y);
        uint2 rv = *(const uint2*)(xw + (size_t)e.x * F + lane * 4);
        float2 v0 = __half22float2(*(__half2*)&rv.x);
        float2 v1 = __half22float2(*(__half2*)&rv.y);
        a0 = fmaf(wv, v0.x, a0); a1 = fmaf(wv, v0.y, a1);
        a2 = fmaf(wv, v1.x, a2); a3 = fmaf(wv, v1.y, a3);
    }
    a0 += b0; a1 += b1; a2 += b2; a3 += b3;
    a0 *= di; a1 *= di; a2 *= di; a3 *= di;   // apply dinv[d] once

    float4 bb = *(const float4*)&bias[lane * 4];
    a0 += bb.x; a1 += bb.y; a2 += bb.z; a3 += bb.w;
    if (RELU) {
        a0 = fmaxf(a0, 0.f); a1 = fmaxf(a1, 0.f);
        a2 = fmaxf(a2, 0.f); a3 = fmaxf(a3, 0.f);
    }
    if constexpr (std::is_same_v<OutT, float>) {
        *(float4*)&out[(size_t)d * F + lane * 4] = make_float4(a0, a1, a2, a3);
    } else {
        __half2 h0 = __floats2half2_rn(a0, a1);
        __half2 h1 = __floats2half2_rn(a2, a3);
        uint2 packed;
        packed.x = *(uint*)&h0;
        packed.y = *(uint*)&h1;
        *(uint2*)&out[(size_t)d * F + lane * 4] = packed;
    }
}

extern "C" void kernel_launch(void* const* d_in, const int* in_sizes, int n_in,
                              void* d_out, int out_size, void* d_ws, size_t ws_size,
                              hipStream_t stream) {
    const float* x  = (const float*)d_in[0];
    const int*   ei = (const int*)d_in[1];
    const float* ew = (const float*)d_in[2];
    const float* W1 = (const float*)d_in[3];
    const float* b1 = (const float*)d_in[4];
    const float* W2 = (const float*)d_in[5];
    const float* b2 = (const float*)d_in[6];
    float* out = (float*)d_out;

    const int H    = in_sizes[4];            // 256
    const int Fout = in_sizes[6];            // 64
    const int Fin  = in_sizes[3] / H;        // 394
    const int N    = in_sizes[0] / Fin;      // 100000
    const int E    = in_sizes[2];            // 1600000

    const int Kpad1 = (Fin + 31) / 32 * 32;  // 416
    const int Kpad2 = (H + 31) / 32 * 32;    // 256

    const int* src = ei;
    const int* dst = ei + E;

    // workspace layout (all sections 16B aligned)
    unsigned long long* packed = (unsigned long long*)d_ws;  // N
    float* dinv   = (float*)(packed + N);         // N
    int*   rowptr = (int*)(dinv + N);             // N+4
    int*   cursor = rowptr + N + 4;               // N+4
    int*   bsums  = cursor + N + 4;               // 256
    int2*  cv     = (int2*)(bsums + 256);         // E int2 (col,val)
    __half* bufA  = (__half*)(cv + E);            // N*H (xw1, later xw2)
    __half* bufB  = bufA + (size_t)N * H;         // N*H (h)
    __half* wt1   = bufB + (size_t)N * H;         // H*Kpad1
    __half* wt2   = wt1 + (size_t)H * Kpad1;      // Fout*Kpad2

    const int NB = (N + SCAN_TILE - 1) / SCAN_TILE;

    // 1. degrees + histogram: ONE packed 64-bit atomic per edge
    init_node<<<(N + 255) / 256, 256, 0, stream>>>(packed, N);
    accum_deg_hist<<<(E + 255) / 256, 256, 0, stream>>>(dst, ew, packed, E);

    // 2. CSR build (dinv fused into scan1; cursor-based fill)
    scan1<<<NB, 256, 0, stream>>>(packed, rowptr, dinv, bsums, N);
    scan2<<<1, 256, 0, stream>>>(bsums, rowptr, NB, N, E);
    scan3<<<NB, 256, 0, stream>>>(rowptr, cursor, bsums, N);
    fill_csr<<<(E + 255) / 256, 256, 0, stream>>>(src, dst, ew, dinv, cursor, cv, E);

    // 3. weight conversions (x conversion fused into GEMM1)
    tohalf_w<<<(H * Kpad1 + 255) / 256, 256, 0, stream>>>(W1, wt1, Fin, H, Kpad1);
    tohalf_w<<<(Fout * Kpad2 + 255) / 256, 256, 0, stream>>>(W2, wt2, H, Fout, Kpad2);

    // 4. xw1 = x @ W1   [N,394](fp32)@[394,256] -> fp16 (depth-1 schedule)
    gemm_f32a<128, 256, 2, 4, 512><<<(N + 127) / 128, 512, 0, stream>>>(
        x, wt1, bufA, N, Fin, Kpad1);

    // 5. h = relu(gather + bias) -> fp16
    gatherh<256, 64, 1, __half><<<(N + 3) / 4, 256, 0, stream>>>(
        rowptr, cv, bufA, dinv, b1, bufB, N);

    // 6. xw2 = h @ W2   [N,256]@[256,64] -> fp16
    gemm_f16<128, 64, 2, 2, 256><<<(N + 127) / 128, 256, 0, stream>>>(bufB, wt2, bufA, N, Kpad2);

    // 7. out = gather + bias -> fp32
    gatherh<64, 16, 0, float><<<(N + 15) / 16, 256, 0, stream>>>(
        rowptr, cv, bufA, dinv, b2, out, N);
}

// Round 17
// 450.367 us; speedup vs baseline: 1.0974x; 1.0361x over previous
//
#include <hip/hip_runtime.h>
#include <hip/hip_bf16.h>
#include <hip/hip_fp16.h>
#include <type_traits>

// ---------------------------------------------------------------------------
// 2-layer GCN. CSR-gather aggregation (fp16 features, fp32 accum, 4x-unrolled
// edge loop; dinv[d] factored out). ONE 64-bit packed atomic per edge; dinv
// fused into scan1; cursor-based CSR fill FUSED INTO the GEMM1 launch as a
// block-role split (fill blocks first, GEMM blocks after) — the two chains
// are data-independent, so fill's fabric-bound waves soak GEMM1's stalls.
// GEMM1: fp32 A, fused convert, depth-1 issue-early. GEMM2: global_load_lds.
// Both: fp16 MFMA fp32-accum, double-buffered LDS, LDS-bounce epilogue.
// ---------------------------------------------------------------------------

typedef _Float16 f16x8 __attribute__((ext_vector_type(8)));
typedef float f32x4 __attribute__((ext_vector_type(4)));

#define DEG_MASK ((1ull << 42) - 1)

__device__ inline void async_copy16(const void* g, void* l) {
    __builtin_amdgcn_global_load_lds(
        (const __attribute__((address_space(1))) void*)g,
        (__attribute__((address_space(3))) void*)l, 16, 0, 0);
}

// ------------------------- graph preprocessing -----------------------------
// packed[i]: bits [63:42] = edge count, bits [41:0] = sum(ew) in 2^-32 fixed pt

// 3-role setup kernel: init packed, convert W1, convert W2
__global__ __launch_bounds__(256) void setup(unsigned long long* packed, int N,
                                             const float* __restrict__ W1,
                                             __half* __restrict__ WT1,
                                             int K1, int N1, int Kpad1,
                                             const float* __restrict__ W2,
                                             __half* __restrict__ WT2,
                                             int K2, int N2, int Kpad2,
                                             int G0, int G1) {
    int b = blockIdx.x;
    if (b < G0) {
        int i = b * 256 + threadIdx.x;
        if (i < N) packed[i] = 0ull;
    } else if (b < G1) {
        int idx = (b - G0) * 256 + threadIdx.x;
        int total = N1 * Kpad1;
        if (idx < total) {
            int n = idx / Kpad1, k = idx % Kpad1;
            float v = (k < K1) ? W1[(size_t)k * N1 + n] : 0.0f;
            WT1[idx] = __float2half(v);
        }
    } else {
        int idx = (b - G1) * 256 + threadIdx.x;
        int total = N2 * Kpad2;
        if (idx < total) {
            int n = idx / Kpad2, k = idx % Kpad2;
            float v = (k < K2) ? W2[(size_t)k * N2 + n] : 0.0f;
            WT2[idx] = __float2half(v);
        }
    }
}

__global__ __launch_bounds__(256) void accum_deg_hist(const int* __restrict__ dst,
                                                      const float* __restrict__ ew,
                                                      unsigned long long* packed, int E) {
    int e = blockIdx.x * 256 + threadIdx.x;
    if (e < E) {
        int d = dst[e];
        unsigned long long add =
            (1ull << 42) + (unsigned long long)(ew[e] * 4294967296.0f);
        atomicAdd(&packed[d], add);
    }
}

#define SCAN_TILE 2048

// exclusive scan of counts; also computes dinv = rsqrt(1 + deg) per node
__global__ __launch_bounds__(256) void scan1(const unsigned long long* __restrict__ packed,
                                             int* __restrict__ rowptr,
                                             float* __restrict__ dinv,
                                             int* __restrict__ bsums, int N) {
    __shared__ int tmp[256];
    int t = threadIdx.x;
    int base = blockIdx.x * SCAN_TILE + t * 8;
    int v[8], s = 0;
#pragma unroll
    for (int j = 0; j < 8; ++j) {
        int idx = base + j;
        if (idx < N) {
            unsigned long long pv = packed[idx];
            v[j] = (int)(pv >> 42);
            dinv[idx] = rsqrtf(1.0f + (float)(pv & DEG_MASK) * (1.0f / 4294967296.0f));
        } else v[j] = 0;
        s += v[j];
    }
    tmp[t] = s;
    __syncthreads();
#pragma unroll
    for (int off = 1; off < 256; off <<= 1) {
        int u = (t >= off) ? tmp[t - off] : 0;
        __syncthreads();
        tmp[t] += u;
        __syncthreads();
    }
    int run = tmp[t] - s;
#pragma unroll
    for (int j = 0; j < 8; ++j) {
        if (base + j < N) rowptr[base + j] = run;
        run += v[j];
    }
    if (t == 255) bsums[blockIdx.x] = tmp[255];
}

__global__ __launch_bounds__(256) void scan2(int* bsums, int* rowptr, int NB, int N, int E) {
    __shared__ int tmp[256];
    int t = threadIdx.x;
    int v = (t < NB) ? bsums[t] : 0;
    tmp[t] = v;
    __syncthreads();
#pragma unroll
    for (int off = 1; off < 256; off <<= 1) {
        int u = (t >= off) ? tmp[t - off] : 0;
        __syncthreads();
        tmp[t] += u;
        __syncthreads();
    }
    if (t < NB) bsums[t] = tmp[t] - v;
    if (t == 0) rowptr[N] = E;
}

// writes final rowptr AND initializes cursor = rowptr
__global__ __launch_bounds__(256) void scan3(int* rowptr, int* cursor,
                                             const int* __restrict__ bsums, int N) {
    int base = blockIdx.x * SCAN_TILE + threadIdx.x * 8;
    int off = bsums[blockIdx.x];
#pragma unroll
    for (int j = 0; j < 8; ++j)
        if (base + j < N) {
            int v = rowptr[base + j] + off;
            rowptr[base + j] = v;
            cursor[base + j] = v;
        }
}

// ------- FUSED: fill_csr (blocks [0,GF)) ∥ GEMM1 (blocks [GF,GF+G1)) -------
// fill: single atomic per edge; val = dinv[src]*ew.
// GEMM1: C[M,BN](fp16) = A[M,K](fp32) @ BT^T, fused A-convert, depth-1
// issue-early; full vmcnt(0) drain per step (safe with variable tail loads).
template <int BM, int BN, int WARPS_M, int WARPS_N, int NT>
__global__ __launch_bounds__(NT) void gemm1_fill(const float* __restrict__ Ax,
                                                 const __half* __restrict__ BT,
                                                 __half* __restrict__ C,
                                                 int M, int K, int Kpad,
                                                 int GF,
                                                 const int* __restrict__ src,
                                                 const int* __restrict__ dst,
                                                 const float* __restrict__ ew,
                                                 const float* __restrict__ dinv,
                                                 int* __restrict__ cursor,
                                                 int2* __restrict__ cv, int E) {
    const int WM = BM / WARPS_M, WN = BN / WARPS_N;
    const int FM = WM / 16, FN = WN / 16;
    const int ACH = BM * 4;              // A chunks (8 halfs each)
    const int BCH = BN * 4;              // B chunks
    static_assert(ACH == NT, "1 A-chunk per thread");
    static_assert(BCH == 2 * NT, "2 B-chunks per thread");
    __shared__ __align__(16) __half lds[2][(ACH + BCH) * 8];

    if ((int)blockIdx.x < GF) {
        // ---------------- fill_csr role (no LDS, no barriers) ----------------
        int e = blockIdx.x * NT + threadIdx.x;
        if (e < E) {
            int d = dst[e], s = src[e];
            int pos = atomicAdd(&cursor[d], 1);
            float v = dinv[s] * ew[e];
            cv[pos] = make_int2(s, __float_as_int(v));
        }
        return;
    }

    // -------------------------- GEMM1 role ---------------------------------
    int tid = threadIdx.x;
    int lane = tid & 63;
    int w = tid >> 6;
    int wr = w / WARPS_N, wc = w % WARPS_N;
    int bm = (blockIdx.x - GF) * BM;
    int lrow = lane & 15;
    int lslot = lane >> 4;

    int arow = tid >> 2, ap = tid & 3;
    int aslot = ap ^ ((arow >> 1) & 3);
    int agrow = bm + arow; if (agrow >= M) agrow = M - 1;
    const float* abase = Ax + (size_t)agrow * K;

    const __half* bsrc[2];
#pragma unroll
    for (int i = 0; i < 2; ++i) {
        int c = tid + i * NT;
        int row = c >> 2, p = c & 3;
        bsrc[i] = BT + (size_t)row * Kpad + (size_t)((p ^ ((row >> 1) & 3)) * 8);
    }

    f32x4 acc[FM][FN];
#pragma unroll
    for (int m = 0; m < FM; ++m)
#pragma unroll
        for (int n = 0; n < FN; ++n) acc[m][n] = (f32x4){0.f, 0.f, 0.f, 0.f};

    float2 ar[4];
    auto loadA = [&](int s) {
        int gk = s * 32 + aslot * 8;
        if (gk + 8 <= K) {
            const float* p = abase + gk;  // 8B-aligned always
            ar[0] = *(const float2*)p;
            ar[1] = *(const float2*)(p + 2);
            ar[2] = *(const float2*)(p + 4);
            ar[3] = *(const float2*)(p + 6);
        } else {
            float t[8];
#pragma unroll
            for (int j = 0; j < 8; ++j) t[j] = (gk + j < K) ? abase[gk + j] : 0.0f;
            ar[0] = make_float2(t[0], t[1]);
            ar[1] = make_float2(t[2], t[3]);
            ar[2] = make_float2(t[4], t[5]);
            ar[3] = make_float2(t[6], t[7]);
        }
    };
    auto writeA = [&](int buf) {
        union { __half2 h[4]; uint4 u; } pk;
#pragma unroll
        for (int j = 0; j < 4; ++j) pk.h[j] = __floats2half2_rn(ar[j].x, ar[j].y);
        *(uint4*)&lds[buf][(size_t)tid * 8] = pk.u;
    };
    auto stageB = [&](int buf) {
#pragma unroll
        for (int i = 0; i < 2; ++i) {
            async_copy16(bsrc[i], &lds[buf][(size_t)((tid & ~63) + (i + 1) * NT) * 8]);
            bsrc[i] += 32;
        }
    };

    auto compute = [&](int buf) {
        f16x8 af[FM], bf[FN];
#pragma unroll
        for (int m = 0; m < FM; ++m) {
            int row = wr * WM + m * 16 + lrow;
            int p = lslot ^ ((row >> 1) & 3);
            af[m] = *(const f16x8*)&lds[buf][(size_t)(row * 4 + p) * 8];
        }
#pragma unroll
        for (int n = 0; n < FN; ++n) {
            int row = wc * WN + n * 16 + lrow;
            int p = lslot ^ ((row >> 1) & 3);
            bf[n] = *(const f16x8*)&lds[buf][(size_t)(ACH + row * 4 + p) * 8];
        }
#pragma unroll
        for (int m = 0; m < FM; ++m)
#pragma unroll
            for (int n = 0; n < FN; ++n)
                acc[m][n] = __builtin_amdgcn_mfma_f32_16x16x32_f16(af[m], bf[n], acc[m][n], 0, 0, 0);
    };

    const int nsteps = Kpad / 32;
    loadA(0);
    stageB(0);
    asm volatile("s_waitcnt vmcnt(2)" ::: "memory");
    writeA(0);
    asm volatile("s_waitcnt vmcnt(0) lgkmcnt(0)" ::: "memory");
    __builtin_amdgcn_s_barrier();
    for (int s = 0; s < nsteps; ++s) {
        bool more = (s + 1 < nsteps);
        if (more) { loadA(s + 1); stageB((s + 1) & 1); }
        compute(s & 1);
        if (more) {
            asm volatile("s_waitcnt vmcnt(2)" ::: "memory");
            writeA((s + 1) & 1);
            asm volatile("s_waitcnt vmcnt(0) lgkmcnt(0)" ::: "memory");
        }
        __builtin_amdgcn_s_barrier();
    }

    // ---- epilogue: per-wave LDS bounce -> 16B coalesced C stores ----
    __syncthreads();
    {
        const int LW = WN + 8;
        __half* tile = (__half*)lds + (size_t)w * 16 * LW;
        const int CPR = WN / 8;
        const int CHT = (16 * CPR) / 64;
#pragma unroll
        for (int m = 0; m < FM; ++m) {
            int rb = bm + wr * WM + m * 16;
#pragma unroll
            for (int n = 0; n < FN; ++n)
#pragma unroll
                for (int i = 0; i < 4; ++i)
                    tile[((lane >> 4) * 4 + i) * LW + n * 16 + (lane & 15)] =
                        __float2half(acc[m][n][i]);
#pragma unroll
            for (int c = 0; c < CHT; ++c) {
                int ch = lane + c * 64;
                int r = ch / CPR, cc = ch % CPR;
                uint4 v = *(uint4*)&tile[r * LW + cc * 8];
                int grow = rb + r;
                if (grow < M)
                    *(uint4*)&C[(size_t)grow * BN + wc * WN + cc * 8] = v;
            }
        }
    }
}

// ---------------- GEMM2: fp16 A, all-global_load_lds staging ---------------
template <int BM, int BN, int WARPS_M, int WARPS_N, int NT>
__global__ __launch_bounds__(NT) void gemm_f16(const __half* __restrict__ Ah,
                                               const __half* __restrict__ BT,
                                               __half* __restrict__ C,
                                               int M, int Kpad) {
    const int WM = BM / WARPS_M, WN = BN / WARPS_N;
    const int FM = WM / 16, FN = WN / 16;
    const int ACH = BM * 4;
    const int BCH = BN * 4;
    const int TOTCH = ACH + BCH;
    const int CH = TOTCH / NT;
    static_assert(CH == 3, "vmcnt(3) hardcoded below");
    __shared__ __align__(16) __half lds[2][TOTCH * 8];

    int tid = threadIdx.x;
    int lane = tid & 63;
    int w = tid >> 6;
    int wr = w / WARPS_N, wc = w % WARPS_N;
    int bm = blockIdx.x * BM;
    int lrow = lane & 15;
    int lslot = lane >> 4;

    const __half* srcp[CH];
#pragma unroll
    for (int i = 0; i < CH; ++i) {
        int ch = tid + i * NT;
        if (ch < ACH) {
            int c = ch, row = c >> 2;
            int grow = bm + row;
            if (grow >= M) grow = M - 1;
            srcp[i] = Ah + (size_t)grow * Kpad + (size_t)(((c & 3) ^ ((row >> 1) & 3)) * 8);
        } else {
            int c = ch - ACH, row = c >> 2;
            srcp[i] = BT + (size_t)row * Kpad + (size_t)(((c & 3) ^ ((row >> 1) & 3)) * 8);
        }
    }

    f32x4 acc[FM][FN];
#pragma unroll
    for (int m = 0; m < FM; ++m)
#pragma unroll
        for (int n = 0; n < FN; ++n) acc[m][n] = (f32x4){0.f, 0.f, 0.f, 0.f};

    auto stage = [&](int buf) {
#pragma unroll
        for (int i = 0; i < CH; ++i) {
            async_copy16(srcp[i], &lds[buf][(size_t)((tid & ~63) + i * NT) * 8]);
            srcp[i] += 32;
        }
    };

    auto compute = [&](int buf) {
        f16x8 af[FM], bf[FN];
#pragma unroll
        for (int m = 0; m < FM; ++m) {
            int row = wr * WM + m * 16 + lrow;
            int p = lslot ^ ((row >> 1) & 3);
            af[m] = *(const f16x8*)&lds[buf][(size_t)(row * 4 + p) * 8];
        }
#pragma unroll
        for (int n = 0; n < FN; ++n) {
            int row = wc * WN + n * 16 + lrow;
            int p = lslot ^ ((row >> 1) & 3);
            bf[n] = *(const f16x8*)&lds[buf][(size_t)(ACH + row * 4 + p) * 8];
        }
#pragma unroll
        for (int m = 0; m < FM; ++m)
#pragma unroll
            for (int n = 0; n < FN; ++n)
                acc[m][n] = __builtin_amdgcn_mfma_f32_16x16x32_f16(af[m], bf[n], acc[m][n], 0, 0, 0);
    };

    const int nsteps = Kpad / 32;
    stage(0);
    for (int s = 0; s < nsteps; ++s) {
        if (s + 1 < nsteps) {
            stage((s + 1) & 1);
            asm volatile("s_waitcnt vmcnt(3)" ::: "memory");
        } else {
            asm volatile("s_waitcnt vmcnt(0)" ::: "memory");
        }
        __builtin_amdgcn_s_barrier();
        compute(s & 1);
        __builtin_amdgcn_s_barrier();
    }

    __syncthreads();
    {
        const int LW = WN + 8;
        __half* tile = (__half*)lds + (size_t)w * 16 * LW;
        const int CPR = WN / 8;
        const int CHT = (16 * CPR) / 64;
#pragma unroll
        for (int m = 0; m < FM; ++m) {
            int rb = bm + wr * WM + m * 16;
#pragma unroll
            for (int n = 0; n < FN; ++n)
#pragma unroll
                for (int i = 0; i < 4; ++i)
                    tile[((lane >> 4) * 4 + i) * LW + n * 16 + (lane & 15)] =
                        __float2half(acc[m][n][i]);
#pragma unroll
            for (int c = 0; c < CHT; ++c) {
                int ch = lane + c * 64;
                int r = ch / CPR, cc = ch % CPR;
                uint4 v = *(uint4*)&tile[r * LW + cc * 8];
                int grow = rb + r;
                if (grow < M)
                    *(uint4*)&C[(size_t)grow * BN + wc * WN + cc * 8] = v;
            }
        }
    }
}

// ---- gather aggregation (fp16 features, fp32 accum, 4x unrolled) ----------
// out[d] = bias + dinv[d]*( dinv[d]*xw[d] + sum_p val[p]*xw[col[p]] )  (; relu)
template <int F, int LPN, int RELU, typename OutT>
__global__ __launch_bounds__(256) void gatherh(const int* __restrict__ rowptr,
                                               const int2* __restrict__ cv,
                                               const __half* __restrict__ xw,
                                               const float* __restrict__ dinv,
                                               const float* __restrict__ bias,
                                               OutT* __restrict__ out, int N) {
    const int NPB = 256 / LPN;
    int d = blockIdx.x * NPB + threadIdx.x / LPN;
    if (d >= N) return;
    int lane = threadIdx.x % LPN;

    float di = dinv[d];
    uint2 raw = *(const uint2*)(xw + (size_t)d * F + lane * 4);
    float2 u0 = __half22float2(*(__half2*)&raw.x);
    float2 u1 = __half22float2(*(__half2*)&raw.y);
    float a0 = di * u0.x, a1 = di * u0.y, a2 = di * u1.x, a3 = di * u1.y;
    float b0 = 0.f, b1 = 0.f, b2 = 0.f, b3 = 0.f;

    int p = rowptr[d], p1 = rowptr[d + 1];
    for (; p + 4 <= p1; p += 4) {
        int2 e0 = cv[p], e1 = cv[p + 1], e2 = cv[p + 2], e3 = cv[p + 3];
        uint2 r0 = *(const uint2*)(xw + (size_t)e0.x * F + lane * 4);
        uint2 r1 = *(const uint2*)(xw + (size_t)e1.x * F + lane * 4);
        uint2 r2 = *(const uint2*)(xw + (size_t)e2.x * F + lane * 4);
        uint2 r3 = *(const uint2*)(xw + (size_t)e3.x * F + lane * 4);
        float w0 = __int_as_float(e0.y), w1 = __int_as_float(e1.y);
        float w2 = __int_as_float(e2.y), w3 = __int_as_float(e3.y);
        {
            float2 v0 = __half22float2(*(__half2*)&r0.x);
            float2 v1 = __half22float2(*(__half2*)&r0.y);
            a0 = fmaf(w0, v0.x, a0); a1 = fmaf(w0, v0.y, a1);
            a2 = fmaf(w0, v1.x, a2); a3 = fmaf(w0, v1.y, a3);
        }
        {
            float2 v0 = __half22float2(*(__half2*)&r1.x);
            float2 v1 = __half22float2(*(__half2*)&r1.y);
            b0 = fmaf(w1, v0.x, b0); b1 = fmaf(w1, v0.y, b1);
            b2 = fmaf(w1, v1.x, b2); b3 = fmaf(w1, v1.y, b3);
        }
        {
            float2 v0 = __half22float2(*(__half2*)&r2.x);
            float2 v1 = __half22float2(*(__half2*)&r2.y);
            a0 = fmaf(w2, v0.x, a0); a1 = fmaf(w2, v0.y, a1);
            a2 = fmaf(w2, v1.x, a2); a3 = fmaf(w2, v1.y, a3);
        }
        {
            float2 v0 = __half22float2(*(__half2*)&r3.x);
            float2 v1 = __half22float2(*(__half2*)&r3.y);
            b0 = fmaf(w3, v0.x, b0); b1 = fmaf(w3, v0.y, b1);
            b2 = fmaf(w3, v1.x, b2); b3 = fmaf(w3, v1.y, b3);
        }
    }
    for (; p < p1; ++p) {
        int2 e = cv[p];
        float wv = __int_as_float(e.y);
        uint2 rv = *(const uint2*)(xw + (size_t)e.x * F + lane * 4);
        float2 v0 = __half22float2(*(__half2*)&rv.x);
        float2 v1 = __half22float2(*(__half2*)&rv.y);
        a0 = fmaf(wv, v0.x, a0); a1 = fmaf(wv, v0.y, a1);
        a2 = fmaf(wv, v1.x, a2); a3 = fmaf(wv, v1.y, a3);
    }
    a0 += b0; a1 += b1; a2 += b2; a3 += b3;
    a0 *= di; a1 *= di; a2 *= di; a3 *= di;

    float4 bb = *(const float4*)&bias[lane * 4];
    a0 += bb.x; a1 += bb.y; a2 += bb.z; a3 += bb.w;
    if (RELU) {
        a0 = fmaxf(a0, 0.f); a1 = fmaxf(a1, 0.f);
        a2 = fmaxf(a2, 0.f); a3 = fmaxf(a3, 0.f);
    }
    if constexpr (std::is_same_v<OutT, float>) {
        *(float4*)&out[(size_t)d * F + lane * 4] = make_float4(a0, a1, a2, a3);
    } else {
        __half2 h0 = __floats2half2_rn(a0, a1);
        __half2 h1 = __floats2half2_rn(a2, a3);
        uint2 packed;
        packed.x = *(uint*)&h0;
        packed.y = *(uint*)&h1;
        *(uint2*)&out[(size_t)d * F + lane * 4] = packed;
    }
}

extern "C" void kernel_launch(void* const* d_in, const int* in_sizes, int n_in,
                              void* d_out, int out_size, void* d_ws, size_t ws_size,
                              hipStream_t stream) {
    const float* x  = (const float*)d_in[0];
    const int*   ei = (const int*)d_in[1];
    const float* ew = (const float*)d_in[2];
    const float* W1 = (const float*)d_in[3];
    const float* b1 = (const float*)d_in[4];
    const float* W2 = (const float*)d_in[5];
    const float* b2 = (const float*)d_in[6];
    float* out = (float*)d_out;

    const int H    = in_sizes[4];            // 256
    const int Fout = in_sizes[6];            // 64
    const int Fin  = in_sizes[3] / H;        // 394
    const int N    = in_sizes[0] / Fin;      // 100000
    const int E    = in_sizes[2];            // 1600000

    const int Kpad1 = (Fin + 31) / 32 * 32;  // 416
    const int Kpad2 = (H + 31) / 32 * 32;    // 256

    const int* src = ei;
    const int* dst = ei + E;

    // workspace layout (all sections 16B aligned)
    unsigned long long* packed = (unsigned long long*)d_ws;  // N
    float* dinv   = (float*)(packed + N);         // N
    int*   rowptr = (int*)(dinv + N);             // N+4
    int*   cursor = rowptr + N + 4;               // N+4
    int*   bsums  = cursor + N + 4;               // 256
    int2*  cv     = (int2*)(bsums + 256);         // E int2 (col,val)
    __half* bufA  = (__half*)(cv + E);            // N*H (xw1, later xw2)
    __half* bufB  = bufA + (size_t)N * H;         // N*H (h)
    __half* wt1   = bufB + (size_t)N * H;         // H*Kpad1
    __half* wt2   = wt1 + (size_t)H * Kpad1;      // Fout*Kpad2

    const int NB = (N + SCAN_TILE - 1) / SCAN_TILE;

    // 1. setup: init packed + convert W1 + convert W2 (one launch)
    {
        int g0 = (N + 255) / 256;
        int g1 = (H * Kpad1 + 255) / 256;
        int g2 = (Fout * Kpad2 + 255) / 256;
        setup<<<g0 + g1 + g2, 256, 0, stream>>>(packed, N,
                                                W1, wt1, Fin, H, Kpad1,
                                                W2, wt2, H, Fout, Kpad2,
                                                g0, g0 + g1);
    }

    // 2. degrees + histogram: ONE packed 64-bit atomic per edge
    accum_deg_hist<<<(E + 255) / 256, 256, 0, stream>>>(dst, ew, packed, E);

    // 3. CSR scan (dinv fused into scan1)
    scan1<<<NB, 256, 0, stream>>>(packed, rowptr, dinv, bsums, N);
    scan2<<<1, 256, 0, stream>>>(bsums, rowptr, NB, N, E);
    scan3<<<NB, 256, 0, stream>>>(rowptr, cursor, bsums, N);

    // 4. FUSED: fill_csr (fill-first) ∥ xw1 = x @ W1 -> fp16
    {
        int GF = (E + 511) / 512;
        int G1 = (N + 127) / 128;
        gemm1_fill<128, 256, 2, 4, 512><<<GF + G1, 512, 0, stream>>>(
            x, wt1, bufA, N, Fin, Kpad1,
            GF, src, dst, ew, dinv, cursor, cv, E);
    }

    // 5. h = relu(gather + bias) -> fp16
    gatherh<256, 64, 1, __half><<<(N + 3) / 4, 256, 0, stream>>>(
        rowptr, cv, bufA, dinv, b1, bufB, N);

    // 6. xw2 = h @ W2   [N,256]@[256,64] -> fp16
    gemm_f16<128, 64, 2, 2, 256><<<(N + 127) / 128, 256, 0, stream>>>(bufB, wt2, bufA, N, Kpad2);

    // 7. out = gather + bias -> fp32
    gatherh<64, 16, 0, float><<<(N + 15) / 16, 256, 0, stream>>>(
        rowptr, cv, bufA, dinv, b2, out, N);
}

// Round 19
// 442.161 us; speedup vs baseline: 1.1177x; 1.0186x over previous
//
#include <hip/hip_runtime.h>
#include <hip/hip_bf16.h>
#include <hip/hip_fp16.h>
#include <type_traits>

// ---------------------------------------------------------------------------
// 2-layer GCN. CSR-gather aggregation (fp16 features, fp32 accum, 4x-unrolled
// edge loop; dinv[d] factored out). ONE 64-bit packed atomic per edge; dinv
// fused into scan1; cursor-based CSR fill FUSED with GEMM1 (block-role split).
// GEMM1: SINGLE-buffered LDS (24KB -> 4 blocks/CU = 32 waves, 100% wave cap;
// R17 measured 48KB dbuf at 34% occupancy, everything stalled). A-loads for
// s+1 issued before compute(s); full vmcnt(0) drain per step (tail-safe).
// GEMM2: fp16 A via global_load_lds (counted vmcnt(3)), double-buffered.
// ---------------------------------------------------------------------------

typedef _Float16 f16x8 __attribute__((ext_vector_type(8)));
typedef float f32x4 __attribute__((ext_vector_type(4)));

#define DEG_MASK ((1ull << 42) - 1)

__device__ inline void async_copy16(const void* g, void* l) {
    __builtin_amdgcn_global_load_lds(
        (const __attribute__((address_space(1))) void*)g,
        (__attribute__((address_space(3))) void*)l, 16, 0, 0);
}

// ------------------------- graph preprocessing -----------------------------
// packed[i]: bits [63:42] = edge count, bits [41:0] = sum(ew) in 2^-32 fixed pt

// 3-role setup kernel: init packed, convert W1, convert W2
__global__ __launch_bounds__(256) void setup(unsigned long long* packed, int N,
                                             const float* __restrict__ W1,
                                             __half* __restrict__ WT1,
                                             int K1, int N1, int Kpad1,
                                             const float* __restrict__ W2,
                                             __half* __restrict__ WT2,
                                             int K2, int N2, int Kpad2,
                                             int G0, int G1) {
    int b = blockIdx.x;
    if (b < G0) {
        int i = b * 256 + threadIdx.x;
        if (i < N) packed[i] = 0ull;
    } else if (b < G1) {
        int idx = (b - G0) * 256 + threadIdx.x;
        int total = N1 * Kpad1;
        if (idx < total) {
            int n = idx / Kpad1, k = idx % Kpad1;
            float v = (k < K1) ? W1[(size_t)k * N1 + n] : 0.0f;
            WT1[idx] = __float2half(v);
        }
    } else {
        int idx = (b - G1) * 256 + threadIdx.x;
        int total = N2 * Kpad2;
        if (idx < total) {
            int n = idx / Kpad2, k = idx % Kpad2;
            float v = (k < K2) ? W2[(size_t)k * N2 + n] : 0.0f;
            WT2[idx] = __float2half(v);
        }
    }
}

__global__ __launch_bounds__(256) void accum_deg_hist(const int* __restrict__ dst,
                                                      const float* __restrict__ ew,
                                                      unsigned long long* packed, int E) {
    int e = blockIdx.x * 256 + threadIdx.x;
    if (e < E) {
        int d = dst[e];
        unsigned long long add =
            (1ull << 42) + (unsigned long long)(ew[e] * 4294967296.0f);
        atomicAdd(&packed[d], add);
    }
}

#define SCAN_TILE 2048

// exclusive scan of counts; also computes dinv = rsqrt(1 + deg) per node
__global__ __launch_bounds__(256) void scan1(const unsigned long long* __restrict__ packed,
                                             int* __restrict__ rowptr,
                                             float* __restrict__ dinv,
                                             int* __restrict__ bsums, int N) {
    __shared__ int tmp[256];
    int t = threadIdx.x;
    int base = blockIdx.x * SCAN_TILE + t * 8;
    int v[8], s = 0;
#pragma unroll
    for (int j = 0; j < 8; ++j) {
        int idx = base + j;
        if (idx < N) {
            unsigned long long pv = packed[idx];
            v[j] = (int)(pv >> 42);
            dinv[idx] = rsqrtf(1.0f + (float)(pv & DEG_MASK) * (1.0f / 4294967296.0f));
        } else v[j] = 0;
        s += v[j];
    }
    tmp[t] = s;
    __syncthreads();
#pragma unroll
    for (int off = 1; off < 256; off <<= 1) {
        int u = (t >= off) ? tmp[t - off] : 0;
        __syncthreads();
        tmp[t] += u;
        __syncthreads();
    }
    int run = tmp[t] - s;
#pragma unroll
    for (int j = 0; j < 8; ++j) {
        if (base + j < N) rowptr[base + j] = run;
        run += v[j];
    }
    if (t == 255) bsums[blockIdx.x] = tmp[255];
}

__global__ __launch_bounds__(256) void scan2(int* bsums, int* rowptr, int NB, int N, int E) {
    __shared__ int tmp[256];
    int t = threadIdx.x;
    int v = (t < NB) ? bsums[t] : 0;
    tmp[t] = v;
    __syncthreads();
#pragma unroll
    for (int off = 1; off < 256; off <<= 1) {
        int u = (t >= off) ? tmp[t - off] : 0;
        __syncthreads();
        tmp[t] += u;
        __syncthreads();
    }
    if (t < NB) bsums[t] = tmp[t] - v;
    if (t == 0) rowptr[N] = E;
}

// writes final rowptr AND initializes cursor = rowptr
__global__ __launch_bounds__(256) void scan3(int* rowptr, int* cursor,
                                             const int* __restrict__ bsums, int N) {
    int base = blockIdx.x * SCAN_TILE + threadIdx.x * 8;
    int off = bsums[blockIdx.x];
#pragma unroll
    for (int j = 0; j < 8; ++j)
        if (base + j < N) {
            int v = rowptr[base + j] + off;
            rowptr[base + j] = v;
            cursor[base + j] = v;
        }
}

// ------- FUSED: fill_csr (blocks [0,GF)) ∥ GEMM1 (blocks [GF,GF+G1)) -------
// fill: single atomic per edge; val = dinv[src]*ew.
// GEMM1: C[M,BN](fp16) = A[M,K](fp32) @ BT^T, fused A-convert, SINGLE-buffer
// LDS (24KB); A-loads issue-early; full vmcnt(0) drain per step (tail-safe).
template <int BM, int BN, int WARPS_M, int WARPS_N, int NT>
__global__ __launch_bounds__(NT) void gemm1_fill(const float* __restrict__ Ax,
                                                 const __half* __restrict__ BT,
                                                 __half* __restrict__ C,
                                                 int M, int K, int Kpad,
                                                 int GF,
                                                 const int* __restrict__ src,
                                                 const int* __restrict__ dst,
                                                 const float* __restrict__ ew,
                                                 const float* __restrict__ dinv,
                                                 int* __restrict__ cursor,
                                                 int2* __restrict__ cv, int E) {
    const int WM = BM / WARPS_M, WN = BN / WARPS_N;
    const int FM = WM / 16, FN = WN / 16;
    const int ACH = BM * 4;              // A chunks (8 halfs each)
    const int BCH = BN * 4;              // B chunks
    static_assert(ACH == NT, "1 A-chunk per thread");
    static_assert(BCH == 2 * NT, "2 B-chunks per thread");
    __shared__ __align__(16) __half lds[(ACH + BCH) * 8];   // SINGLE buffer, 24KB

    if ((int)blockIdx.x < GF) {
        // ---------------- fill_csr role (no barriers) ----------------
        int e = blockIdx.x * NT + threadIdx.x;
        if (e < E) {
            int d = dst[e], s = src[e];
            int pos = atomicAdd(&cursor[d], 1);
            float v = dinv[s] * ew[e];
            cv[pos] = make_int2(s, __float_as_int(v));
        }
        return;
    }

    // -------------------------- GEMM1 role ---------------------------------
    int tid = threadIdx.x;
    int lane = tid & 63;
    int w = tid >> 6;
    int wr = w / WARPS_N, wc = w % WARPS_N;
    int bm = (blockIdx.x - GF) * BM;
    int lrow = lane & 15;
    int lslot = lane >> 4;

    int arow = tid >> 2, ap = tid & 3;
    int aslot = ap ^ ((arow >> 1) & 3);
    int agrow = bm + arow; if (agrow >= M) agrow = M - 1;
    const float* abase = Ax + (size_t)agrow * K;

    const __half* bsrc[2];
#pragma unroll
    for (int i = 0; i < 2; ++i) {
        int c = tid + i * NT;
        int row = c >> 2, p = c & 3;
        bsrc[i] = BT + (size_t)row * Kpad + (size_t)((p ^ ((row >> 1) & 3)) * 8);
    }

    f32x4 acc[FM][FN];
#pragma unroll
    for (int m = 0; m < FM; ++m)
#pragma unroll
        for (int n = 0; n < FN; ++n) acc[m][n] = (f32x4){0.f, 0.f, 0.f, 0.f};

    float2 ar[4];
    auto loadA = [&](int s) {
        int gk = s * 32 + aslot * 8;
        if (gk + 8 <= K) {
            const float* p = abase + gk;  // 8B-aligned always
            ar[0] = *(const float2*)p;
            ar[1] = *(const float2*)(p + 2);
            ar[2] = *(const float2*)(p + 4);
            ar[3] = *(const float2*)(p + 6);
        } else {
            float t[8];
#pragma unroll
            for (int j = 0; j < 8; ++j) t[j] = (gk + j < K) ? abase[gk + j] : 0.0f;
            ar[0] = make_float2(t[0], t[1]);
            ar[1] = make_float2(t[2], t[3]);
            ar[2] = make_float2(t[4], t[5]);
            ar[3] = make_float2(t[6], t[7]);
        }
    };
    auto writeA = [&]() {
        union { __half2 h[4]; uint4 u; } pk;
#pragma unroll
        for (int j = 0; j < 4; ++j) pk.h[j] = __floats2half2_rn(ar[j].x, ar[j].y);
        *(uint4*)&lds[(size_t)tid * 8] = pk.u;
    };
    auto stageB = [&]() {
#pragma unroll
        for (int i = 0; i < 2; ++i) {
            async_copy16(bsrc[i], &lds[(size_t)((tid & ~63) + (i + 1) * NT) * 8]);
            bsrc[i] += 32;
        }
    };

    auto compute = [&]() {
        f16x8 af[FM], bf[FN];
#pragma unroll
        for (int m = 0; m < FM; ++m) {
            int row = wr * WM + m * 16 + lrow;
            int p = lslot ^ ((row >> 1) & 3);
            af[m] = *(const f16x8*)&lds[(size_t)(row * 4 + p) * 8];
        }
#pragma unroll
        for (int n = 0; n < FN; ++n) {
            int row = wc * WN + n * 16 + lrow;
            int p = lslot ^ ((row >> 1) & 3);
            bf[n] = *(const f16x8*)&lds[(size_t)(ACH + row * 4 + p) * 8];
        }
#pragma unroll
        for (int m = 0; m < FM; ++m)
#pragma unroll
            for (int n = 0; n < FN; ++n)
                acc[m][n] = __builtin_amdgcn_mfma_f32_16x16x32_f16(af[m], bf[n], acc[m][n], 0, 0, 0);
    };

    const int nsteps = Kpad / 32;
    // prologue: fill the buffer for step 0
    loadA(0);
    stageB();
    asm volatile("s_waitcnt vmcnt(2)" ::: "memory");   // A regs landed
    writeA();
    asm volatile("s_waitcnt vmcnt(0) lgkmcnt(0)" ::: "memory");
    __builtin_amdgcn_s_barrier();
    for (int s = 0; s < nsteps; ++s) {
        bool more = (s + 1 < nsteps);
        if (more) loadA(s + 1);          // issue A early; regs only, safe now
        compute();
        __builtin_amdgcn_s_barrier();    // all waves done reading LDS
        if (more) {
            stageB();                    // DMA into (single) buffer now safe
            asm volatile("s_waitcnt vmcnt(2)" ::: "memory");   // A landed
            writeA();
            asm volatile("s_waitcnt vmcnt(0) lgkmcnt(0)" ::: "memory");
            __builtin_amdgcn_s_barrier();
        }
    }

    // ---- epilogue: per-wave LDS bounce -> 16B coalesced C stores ----
    __syncthreads();
    {
        const int LW = WN + 8;
        __half* tile = (__half*)lds + (size_t)w * 16 * LW;
        const int CPR = WN / 8;
        const int CHT = (16 * CPR) / 64;
#pragma unroll
        for (int m = 0; m < FM; ++m) {
            int rb = bm + wr * WM + m * 16;
#pragma unroll
            for (int n = 0; n < FN; ++n)
#pragma unroll
                for (int i = 0; i < 4; ++i)
                    tile[((lane >> 4) * 4 + i) * LW + n * 16 + (lane & 15)] =
                        __float2half(acc[m][n][i]);
#pragma unroll
            for (int c = 0; c < CHT; ++c) {
                int ch = lane + c * 64;
                int r = ch / CPR, cc = ch % CPR;
                uint4 v = *(uint4*)&tile[r * LW + cc * 8];
                int grow = rb + r;
                if (grow < M)
                    *(uint4*)&C[(size_t)grow * BN + wc * WN + cc * 8] = v;
            }
        }
    }
}

// ---------------- GEMM2: fp16 A, all-global_load_lds staging ---------------
template <int BM, int BN, int WARPS_M, int WARPS_N, int NT>
__global__ __launch_bounds__(NT) void gemm_f16(const __half* __restrict__ Ah,
                                               const __half* __restrict__ BT,
                                               __half* __restrict__ C,
                                               int M, int Kpad) {
    const int WM = BM / WARPS_M, WN = BN / WARPS_N;
    const int FM = WM / 16, FN = WN / 16;
    const int ACH = BM * 4;
    const int BCH = BN * 4;
    const int TOTCH = ACH + BCH;
    const int CH = TOTCH / NT;
    static_assert(CH == 3, "vmcnt(3) hardcoded below");
    __shared__ __align__(16) __half lds[2][TOTCH * 8];

    int tid = threadIdx.x;
    int lane = tid & 63;
    int w = tid >> 6;
    int wr = w / WARPS_N, wc = w % WARPS_N;
    int bm = blockIdx.x * BM;
    int lrow = lane & 15;
    int lslot = lane >> 4;

    const __half* srcp[CH];
#pragma unroll
    for (int i = 0; i < CH; ++i) {
        int ch = tid + i * NT;
        if (ch < ACH) {
            int c = ch, row = c >> 2;
            int grow = bm + row;
            if (grow >= M) grow = M - 1;
            srcp[i] = Ah + (size_t)grow * Kpad + (size_t)(((c & 3) ^ ((row >> 1) & 3)) * 8);
        } else {
            int c = ch - ACH, row = c >> 2;
            srcp[i] = BT + (size_t)row * Kpad + (size_t)(((c & 3) ^ ((row >> 1) & 3)) * 8);
        }
    }

    f32x4 acc[FM][FN];
#pragma unroll
    for (int m = 0; m < FM; ++m)
#pragma unroll
        for (int n = 0; n < FN; ++n) acc[m][n] = (f32x4){0.f, 0.f, 0.f, 0.f};

    auto stage = [&](int buf) {
#pragma unroll
        for (int i = 0; i < CH; ++i) {
            async_copy16(srcp[i], &lds[buf][(size_t)((tid & ~63) + i * NT) * 8]);
            srcp[i] += 32;
        }
    };

    auto compute = [&](int buf) {
        f16x8 af[FM], bf[FN];
#pragma unroll
        for (int m = 0; m < FM; ++m) {
            int row = wr * WM + m * 16 + lrow;
            int p = lslot ^ ((row >> 1) & 3);
            af[m] = *(const f16x8*)&lds[buf][(size_t)(row * 4 + p) * 8];
        }
#pragma unroll
        for (int n = 0; n < FN; ++n) {
            int row = wc * WN + n * 16 + lrow;
            int p = lslot ^ ((row >> 1) & 3);
            bf[n] = *(const f16x8*)&lds[buf][(size_t)(ACH + row * 4 + p) * 8];
        }
#pragma unroll
        for (int m = 0; m < FM; ++m)
#pragma unroll
            for (int n = 0; n < FN; ++n)
                acc[m][n] = __builtin_amdgcn_mfma_f32_16x16x32_f16(af[m], bf[n], acc[m][n], 0, 0, 0);
    };

    const int nsteps = Kpad / 32;
    stage(0);
    for (int s = 0; s < nsteps; ++s) {
        if (s + 1 < nsteps) {
            stage((s + 1) & 1);
            asm volatile("s_waitcnt vmcnt(3)" ::: "memory");
        } else {
            asm volatile("s_waitcnt vmcnt(0)" ::: "memory");
        }
        __builtin_amdgcn_s_barrier();
        compute(s & 1);
        __builtin_amdgcn_s_barrier();
    }

    __syncthreads();
    {
        const int LW = WN + 8;
        __half* tile = (__half*)lds + (size_t)w * 16 * LW;
        const int CPR = WN / 8;
        const int CHT = (16 * CPR) / 64;
#pragma unroll
        for (int m = 0; m < FM; ++m) {
            int rb = bm + wr * WM + m * 16;
#pragma unroll
            for (int n = 0; n < FN; ++n)
#pragma unroll
                for (int i = 0; i < 4; ++i)
                    tile[((lane >> 4) * 4 + i) * LW + n * 16 + (lane & 15)] =
                        __float2half(acc[m][n][i]);
#pragma unroll
            for (int c = 0; c < CHT; ++c) {
                int ch = lane + c * 64;
                int r = ch / CPR, cc = ch % CPR;
                uint4 v = *(uint4*)&tile[r * LW + cc * 8];
                int grow = rb + r;
                if (grow < M)
                    *(uint4*)&C[(size_t)grow * BN + wc * WN + cc * 8] = v;
            }
        }
    }
}

// ---- gather aggregation (fp16 features, fp32 accum, 4x unrolled) ----------
// out[d] = bias + dinv[d]*( dinv[d]*xw[d] + sum_p val[p]*xw[col[p]] )  (; relu)
template <int F, int LPN, int RELU, typename OutT>
__global__ __launch_bounds__(256) void gatherh(const int* __restrict__ rowptr,
                                               const int2* __restrict__ cv,
                                               const __half* __restrict__ xw,
                                               const float* __restrict__ dinv,
                                               const float* __restrict__ bias,
                                               OutT* __restrict__ out, int N) {
    const int NPB = 256 / LPN;
    int d = blockIdx.x * NPB + threadIdx.x / LPN;
    if (d >= N) return;
    int lane = threadIdx.x % LPN;

    float di = dinv[d];
    uint2 raw = *(const uint2*)(xw + (size_t)d * F + lane * 4);
    float2 u0 = __half22float2(*(__half2*)&raw.x);
    float2 u1 = __half22float2(*(__half2*)&raw.y);
    float a0 = di * u0.x, a1 = di * u0.y, a2 = di * u1.x, a3 = di * u1.y;
    float b0 = 0.f, b1 = 0.f, b2 = 0.f, b3 = 0.f;

    int p = rowptr[d], p1 = rowptr[d + 1];
    for (; p + 4 <= p1; p += 4) {
        int2 e0 = cv[p], e1 = cv[p + 1], e2 = cv[p + 2], e3 = cv[p + 3];
        uint2 r0 = *(const uint2*)(xw + (size_t)e0.x * F + lane * 4);
        uint2 r1 = *(const uint2*)(xw + (size_t)e1.x * F + lane * 4);
        uint2 r2 = *(const uint2*)(xw + (size_t)e2.x * F + lane * 4);
        uint2 r3 = *(const uint2*)(xw + (size_t)e3.x * F + lane * 4);
        float w0 = __int_as_float(e0.y), w1 = __int_as_float(e1.y);
        float w2 = __int_as_float(e2.y), w3 = __int_as_float(e3.y);
        {
            float2 v0 = __half22float2(*(__half2*)&r0.x);
            float2 v1 = __half22float2(*(__half2*)&r0.y);
            a0 = fmaf(w0, v0.x, a0); a1 = fmaf(w0, v0.y, a1);
            a2 = fmaf(w0, v1.x, a2); a3 = fmaf(w0, v1.y, a3);
        }
        {
            float2 v0 = __half22float2(*(__half2*)&r1.x);
            float2 v1 = __half22float2(*(__half2*)&r1.y);
            b0 = fmaf(w1, v0.x, b0); b1 = fmaf(w1, v0.y, b1);
            b2 = fmaf(w1, v1.x, b2); b3 = fmaf(w1, v1.y, b3);
        }
        {
            float2 v0 = __half22float2(*(__half2*)&r2.x);
            float2 v1 = __half22float2(*(__half2*)&r2.y);
            a0 = fmaf(w2, v0.x, a0); a1 = fmaf(w2, v0.y, a1);
            a2 = fmaf(w2, v1.x, a2); a3 = fmaf(w2, v1.y, a3);
        }
        {
            float2 v0 = __half22float2(*(__half2*)&r3.x);
            float2 v1 = __half22float2(*(__half2*)&r3.y);
            b0 = fmaf(w3, v0.x, b0); b1 = fmaf(w3, v0.y, b1);
            b2 = fmaf(w3, v1.x, b2); b3 = fmaf(w3, v1.y, b3);
        }
    }
    for (; p < p1; ++p) {
        int2 e = cv[p];
        float wv = __int_as_float(e.y);
        uint2 rv = *(const uint2*)(xw + (size_t)e.x * F + lane * 4);
        float2 v0 = __half22float2(*(__half2*)&rv.x);
        float2 v1 = __half22float2(*(__half2*)&rv.y);
        a0 = fmaf(wv, v0.x, a0); a1 = fmaf(wv, v0.y, a1);
        a2 = fmaf(wv, v1.x, a2); a3 = fmaf(wv, v1.y, a3);
    }
    a0 += b0; a1 += b1; a2 += b2; a3 += b3;
    a0 *= di; a1 *= di; a2 *= di; a3 *= di;

    float4 bb = *(const float4*)&bias[lane * 4];
    a0 += bb.x; a1 += bb.y; a2 += bb.z; a3 += bb.w;
    if (RELU) {
        a0 = fmaxf(a0, 0.f); a1 = fmaxf(a1, 0.f);
        a2 = fmaxf(a2, 0.f); a3 = fmaxf(a3, 0.f);
    }
    if constexpr (std::is_same_v<OutT, float>) {
        *(float4*)&out[(size_t)d * F + lane * 4] = make_float4(a0, a1, a2, a3);
    } else {
        __half2 h0 = __floats2half2_rn(a0, a1);
        __half2 h1 = __floats2half2_rn(a2, a3);
        uint2 packed;
        packed.x = *(uint*)&h0;
        packed.y = *(uint*)&h1;
        *(uint2*)&out[(size_t)d * F + lane * 4] = packed;
    }
}

extern "C" void kernel_launch(void* const* d_in, const int* in_sizes, int n_in,
                              void* d_out, int out_size, void* d_ws, size_t ws_size,
                              hipStream_t stream) {
    const float* x  = (const float*)d_in[0];
    const int*   ei = (const int*)d_in[1];
    const float* ew = (const float*)d_in[2];
    const float* W1 = (const float*)d_in[3];
    const float* b1 = (const float*)d_in[4];
    const float* W2 = (const float*)d_in[5];
    const float* b2 = (const float*)d_in[6];
    float* out = (float*)d_out;

    const int H    = in_sizes[4];            // 256
    const int Fout = in_sizes[6];            // 64
    const int Fin  = in_sizes[3] / H;        // 394
    const int N    = in_sizes[0] / Fin;      // 100000
    const int E    = in_sizes[2];            // 1600000

    const int Kpad1 = (Fin + 31) / 32 * 32;  // 416
    const int Kpad2 = (H + 31) / 32 * 32;    // 256

    const int* src = ei;
    const int* dst = ei + E;

    // workspace layout (all sections 16B aligned)
    unsigned long long* packed = (unsigned long long*)d_ws;  // N
    float* dinv   = (float*)(packed + N);         // N
    int*   rowptr = (int*)(dinv + N);             // N+4
    int*   cursor = rowptr + N + 4;               // N+4
    int*   bsums  = cursor + N + 4;               // 256
    int2*  cv     = (int2*)(bsums + 256);         // E int2 (col,val)
    __half* bufA  = (__half*)(cv + E);            // N*H (xw1, later xw2)
    __half* bufB  = bufA + (size_t)N * H;         // N*H (h)
    __half* wt1   = bufB + (size_t)N * H;         // H*Kpad1
    __half* wt2   = wt1 + (size_t)H * Kpad1;      // Fout*Kpad2

    const int NB = (N + SCAN_TILE - 1) / SCAN_TILE;

    // 1. setup: init packed + convert W1 + convert W2 (one launch)
    {
        int g0 = (N + 255) / 256;
        int g1 = (H * Kpad1 + 255) / 256;
        int g2 = (Fout * Kpad2 + 255) / 256;
        setup<<<g0 + g1 + g2, 256, 0, stream>>>(packed, N,
                                                W1, wt1, Fin, H, Kpad1,
                                                W2, wt2, H, Fout, Kpad2,
                                                g0, g0 + g1);
    }

    // 2. degrees + histogram: ONE packed 64-bit atomic per edge
    accum_deg_hist<<<(E + 255) / 256, 256, 0, stream>>>(dst, ew, packed, E);

    // 3. CSR scan (dinv fused into scan1)
    scan1<<<NB, 256, 0, stream>>>(packed, rowptr, dinv, bsums, N);
    scan2<<<1, 256, 0, stream>>>(bsums, rowptr, NB, N, E);
    scan3<<<NB, 256, 0, stream>>>(rowptr, cursor, bsums, N);

    // 4. FUSED: fill_csr (fill-first) ∥ xw1 = x @ W1 -> fp16 (single-buffer)
    {
        int GF = (E + 511) / 512;
        int G1 = (N + 127) / 128;
        gemm1_fill<128, 256, 2, 4, 512><<<GF + G1, 512, 0, stream>>>(
            x, wt1, bufA, N, Fin, Kpad1,
            GF, src, dst, ew, dinv, cursor, cv, E);
    }

    // 5. h = relu(gather + bias) -> fp16
    gatherh<256, 64, 1, __half><<<(N + 3) / 4, 256, 0, stream>>>(
        rowptr, cv, bufA, dinv, b1, bufB, N);

    // 6. xw2 = h @ W2   [N,256]@[256,64] -> fp16
    gemm_f16<128, 64, 2, 2, 256><<<(N + 127) / 128, 256, 0, stream>>>(bufB, wt2, bufA, N, Kpad2);

    // 7. out = gather + bias -> fp32
    gatherh<64, 16, 0, float><<<(N + 15) / 16, 256, 0, stream>>>(
        rowptr, cv, bufA, dinv, b2, out, N);
}